// Round 6
// baseline (516.249 us; speedup 1.0000x reference)
//
#include <hip/hip_runtime.h>
#include <hip/hip_bf16.h>

typedef __bf16 bf16_t;
typedef __bf16 bf16x8 __attribute__((ext_vector_type(8)));
typedef __bf16 bf16x4 __attribute__((ext_vector_type(4)));
typedef float  f32x4  __attribute__((ext_vector_type(4)));

#define LDS_DST(p) ((__attribute__((address_space(3))) void*)(p))
#define GLB_SRC(p) ((const __attribute__((address_space(1))) void*)(p))

#define SBAR()   asm volatile("s_barrier" ::: "memory")
#define WVM8()   asm volatile("s_waitcnt vmcnt(8)" ::: "memory")
#define WVM6()   asm volatile("s_waitcnt vmcnt(6)" ::: "memory")
#define WVM2()   asm volatile("s_waitcnt vmcnt(2)" ::: "memory")
#define WVM0()   asm volatile("s_waitcnt vmcnt(0)" ::: "memory")
#define SP1()    __builtin_amdgcn_s_setprio(1)
#define SP0()    __builtin_amdgcn_s_setprio(0)

// ---------------- fp32 -> bf16 convert ----------------
__global__ void __launch_bounds__(256)
f32_to_bf16_kernel(const float* __restrict__ in, bf16_t* __restrict__ out, int n4) {
  int i = blockIdx.x * 256 + threadIdx.x;
  if (i < n4) {
    const float4 v = reinterpret_cast<const float4*>(in)[i];
    bf16x4 o;
    o[0] = (bf16_t)v.x; o[1] = (bf16_t)v.y; o[2] = (bf16_t)v.z; o[3] = (bf16_t)v.w;
    reinterpret_cast<bf16x4*>(out)[i] = o;
  }
}

// -------- mask int32 -> bitmask; bit (32i + b) = mask[32i + b] --------
// one u32 per thread from 8x int4 loads (16B/lane).
__global__ void __launch_bounds__(256)
mask_pack_kernel(const int* __restrict__ mask, unsigned* __restrict__ bits) {
  const long i = (long)blockIdx.x * 256 + threadIdx.x;
  const int4* m4 = reinterpret_cast<const int4*>(mask + i * 32);
  unsigned w = 0;
#pragma unroll
  for (int j = 0; j < 8; ++j) {
    const int4 v = m4[j];
    w |= (v.x != 0 ? 1u : 0u) << (j * 4);
    w |= (v.y != 0 ? 2u : 0u) << (j * 4);
    w |= (v.z != 0 ? 4u : 0u) << (j * 4);
    w |= (v.w != 0 ? 8u : 0u) << (j * 4);
  }
  bits[i] = w;
}

// ---------------- bf16 transpose: in [z][R][C] -> out [z][C][R] ----------------
__global__ void __launch_bounds__(256)
transpose_bf16_kernel(const bf16_t* __restrict__ in, bf16_t* __restrict__ out,
                      int R, int C) {
  __shared__ bf16_t tile[64][72];
  const long base = (long)blockIdx.z * R * C;
  const bf16_t* ib = in + base;
  bf16_t* ob = out + base;
  const int r0 = blockIdx.x * 64, c0 = blockIdx.y * 64;
  const int tid = threadIdx.x;
  const int rr = tid >> 3, cg = tid & 7;
#pragma unroll
  for (int p = 0; p < 2; ++p) {
    int row = p * 32 + rr;
    bf16x8 v = *reinterpret_cast<const bf16x8*>(ib + (long)(r0 + row) * C + c0 + cg * 8);
    *reinterpret_cast<bf16x8*>(&tile[row][cg * 8]) = v;
  }
  __syncthreads();
#pragma unroll
  for (int p = 0; p < 2; ++p) {
    int c = p * 32 + rr;
    bf16x8 v;
#pragma unroll
    for (int i = 0; i < 8; ++i) v[i] = tile[cg * 8 + i][c];
    *reinterpret_cast<bf16x8*>(ob + (long)(c0 + c) * R + r0 + cg * 8) = v;
  }
}

// ============ 256x256 pipelined GEMM (frag-prefetch, 2 barriers/K-tile) ========
// Phase schedule per tile t (quadrants q00,q01,q11,q10):
//  P1: MFMA q00(afX=A0(t), bf0=B0(t));  read B1(t)->bfB;  stage A0(t+2)
//  P2: MFMA q01(afX, bfB);              read A1(t)->afY;  stage B0(t+2); vmcnt(6)+SBAR
//  P3: MFMA q11(afY, bfB);              read A0(t+1)->afX; stage B1(t+2)
//  P4: MFMA q10(afY, bf0); read B0(t+1)->bf0; stage A1(t+2);            vmcnt(6)+SBAR
// Every MFMA operand was ds_read >=1 phase earlier (no lgkm stall on the
// critical path). Each LDS region is read exactly ONCE per tile:
//   A0(t)@P3(t-1), B0(t)@P4(t-1), B1(t)@P1(t), A1(t)@P2(t).
// Stage-overwrites-read hazards (need >=1 barrier between):
//   A0(t+2)@P1(t) vs read@P3(t-1): c2(t-1) OK | B0@P2(t) vs P4(t-1): c2(t-1) OK
//   B1(t+2)@P3(t) vs read@P1(t): c1(t) OK     | A1@P4(t) vs P2(t): c1(t) OK
// vmcnt(6) confirms each stage 3-4 phases after issue, always >=1 barrier
// before its first read (checked per region; prologue pre-stages t0+t1).

__device__ __forceinline__ void read_A(const char* smem, int off, bf16x8 (&af)[8], int xk0) {
#pragma unroll
  for (int mf = 0; mf < 4; ++mf)
#pragma unroll
    for (int kk = 0; kk < 2; ++kk)
      af[mf * 2 + kk] = *reinterpret_cast<const bf16x8*>(
          smem + off + mf * 2048 + (kk ? (xk0 ^ 64) : xk0));
}

__device__ __forceinline__ void read_B(const char* smem, int off, bf16x8 (&bf_)[4], int xk0) {
#pragma unroll
  for (int nf = 0; nf < 2; ++nf)
#pragma unroll
    for (int kk = 0; kk < 2; ++kk)
      bf_[nf * 2 + kk] = *reinterpret_cast<const bf16x8*>(
          smem + off + nf * 2048 + (kk ? (xk0 ^ 64) : xk0));
}

template <int MH, int NH>
__device__ __forceinline__ void mfma_q(const bf16x8 (&af)[8], const bf16x8 (&bf_)[4],
                                       f32x4 (&acc)[8][4]) {
#pragma unroll
  for (int mf = 0; mf < 4; ++mf)
#pragma unroll
    for (int nf = 0; nf < 2; ++nf)
#pragma unroll
      for (int kk = 0; kk < 2; ++kk)
        acc[MH * 4 + mf][NH * 2 + nf] = __builtin_amdgcn_mfma_f32_16x16x32_bf16(
            af[mf * 2 + kk], bf_[nf * 2 + kk], acc[MH * 4 + mf][NH * 2 + nf], 0, 0, 0);
}

// staging: per-thread global base (pA/pB) + wave-uniform scalar offset;
// LDS dest = wave-uniform base (lane*16 is implicit HW behavior).
#define STAGE_A(slot, mh, kt) do {                                            \
  _Pragma("unroll") for (int j_ = 0; j_ < 2; ++j_)                            \
    __builtin_amdgcn_global_load_lds(                                         \
        GLB_SRC(pA + (long)(j_ * 128 + (mh) * 64) * K + (kt)),                \
        LDS_DST(smem + (slot) * 65536 + (arow0 + j_ * 128 + (mh) * 64) * 128),\
        16, 0, 0);                                                            \
} while (0)

#define STAGE_B(slot, nh, kt) do {                                            \
  _Pragma("unroll") for (int j_ = 0; j_ < 2; ++j_)                            \
    __builtin_amdgcn_global_load_lds(                                         \
        GLB_SRC(pB + (long)(j_ * 128 + (nh) * 32) * K + (kt)),                \
        LDS_DST(smem + (slot) * 65536 + 32768 +                               \
                (brow0 + j_ * 128 + (nh) * 32) * 128),                        \
        16, 0, 0);                                                            \
} while (0)

// MODE 0: bf16 out = acc + bias[n];  MODE 1: bf16 out = maskbit?sigmoid(acc):0;
// MODE 2: f32 out = acc
template <int MODE>
__global__ void __launch_bounds__(512, 2)
gemm8p_kernel(const bf16_t* __restrict__ A, const bf16_t* __restrict__ B,
              const float* __restrict__ bias, const unsigned* __restrict__ maskbits,
              void* __restrict__ Cout, int M, int N, int K,
              long sA, long sB, long sC, long sMask) {
  __shared__ __align__(1024) char smem[131072];
  const int bz = blockIdx.z;
  const bf16_t* Ab = A + bz * sA;
  const bf16_t* Bb = B + bz * sB;
  const int bm = blockIdx.x * 256, bn = blockIdx.y * 256;
  const int tid = threadIdx.x;
  const int wave = tid >> 6, lane = tid & 63;
  const int wr = wave >> 2, wc = wave & 3;
  const int l15 = lane & 15, lg = lane >> 4;
  const int xk0 = (lg * 16) ^ ((lane & 7) << 4);
  const int NT = K >> 6;

  // staging bases
  const int lr = lane >> 3;
  const int cgs = ((lane & 7) ^ lr) * 8;
  const int arow0 = wave * 8;
  const int brow0 = (wave >> 2) * 64 + (wave & 3) * 8;
  const bf16_t* pA = Ab + (long)(bm + arow0 + lr) * K + cgs;
  const bf16_t* pB = Bb + (long)(bn + brow0 + lr) * K + cgs;

  // ds_read base offsets
  const int aoff = wr * 16384 + l15 * 128;          // + slot*65536 + mh*8192
  const int boff = 32768 + wc * 8192 + l15 * 128;   // + slot*65536 + nh*4096

  f32x4 acc[8][4] = {};
  bf16x8 afX[8], afY[8], bfB[4], bf0[4];

  // ---- prologue: stage tiles 0 and 1 fully ----
  STAGE_A(0, 0, 0); STAGE_B(0, 0, 0); STAGE_B(0, 1, 0); STAGE_A(0, 1, 0);
  STAGE_A(1, 0, 64); STAGE_B(1, 0, 64); STAGE_B(1, 1, 64); STAGE_A(1, 1, 64);
  WVM8();   // tile0's 8 instrs landed
  SBAR();
  read_A(smem, aoff + 0, afX, xk0);   // A0(t0)
  read_B(smem, boff + 0, bf0, xk0);   // B0(t0)

  int slot = 0;
  for (int t = 0; t + 2 < NT; ++t) {
    const int so = slot * 65536, sn = (slot ^ 1) * 65536;
    const int k2 = (t + 2) << 6;
    // P1
    read_B(smem, so + boff + 4096, bfB, xk0);
    STAGE_A(slot, 0, k2);
    SP1(); mfma_q<0, 0>(afX, bf0, acc); SP0();
    // P2
    read_A(smem, so + aoff + 8192, afY, xk0);
    STAGE_B(slot, 0, k2);
    SP1(); mfma_q<0, 1>(afX, bfB, acc); SP0();
    WVM6(); SBAR();                               // c1
    // P3
    read_A(smem, sn + aoff + 0, afX, xk0);
    STAGE_B(slot, 1, k2);
    SP1(); mfma_q<1, 1>(afY, bfB, acc); SP0();
    // P4 (MFMA first: bf0 still holds B0(t); then refill bf0 with B0(t+1))
    SP1(); mfma_q<1, 0>(afY, bf0, acc); SP0();
    read_B(smem, sn + boff + 0, bf0, xk0);
    STAGE_A(slot, 1, k2);
    WVM6(); SBAR();                               // c2
    slot ^= 1;
  }

  // ---- drain: tiles NT-2 (so), NT-1 (sn); no staging ----
  {
    const int so = slot * 65536, sn = (slot ^ 1) * 65536;
    read_B(smem, so + boff + 4096, bfB, xk0);
    SP1(); mfma_q<0, 0>(afX, bf0, acc); SP0();
    read_A(smem, so + aoff + 8192, afY, xk0);
    SP1(); mfma_q<0, 1>(afX, bfB, acc); SP0();
    WVM2(); SBAR();
    read_A(smem, sn + aoff + 0, afX, xk0);
    SP1(); mfma_q<1, 1>(afY, bfB, acc); SP0();
    SP1(); mfma_q<1, 0>(afY, bf0, acc); SP0();
    read_B(smem, sn + boff + 0, bf0, xk0);
    WVM0(); SBAR();
    // last tile
    read_B(smem, sn + boff + 4096, bfB, xk0);
    SP1(); mfma_q<0, 0>(afX, bf0, acc); SP0();
    read_A(smem, sn + aoff + 8192, afY, xk0);
    SP1(); mfma_q<0, 1>(afX, bfB, acc); SP0();
    SP1(); mfma_q<1, 1>(afY, bfB, acc); SP0();
    SP1(); mfma_q<1, 0>(afY, bf0, acc); SP0();
  }

  // ---- C-write: 4 rounds of 64-row LDS rearrange, coalesced I/O ----
  // (fully unrolled: acc indices must stay compile-time -- rule #20)
  float* eb = (float*)smem;
  const int lrow = tid >> 3, t7 = tid & 7;
#pragma unroll
  for (int rd = 0; rd < 4; ++rd) {
    __syncthreads();
#pragma unroll
    for (int fi = 0; fi < 2; ++fi)
#pragma unroll
      for (int nf = 0; nf < 4; ++nf)
#pragma unroll
        for (int r = 0; r < 4; ++r) {
          const int lr2 = wr * 32 + fi * 16 + lg * 4 + r;
          eb[lr2 * 256 + wc * 64 + nf * 16 + l15] = acc[rd * 2 + fi][nf][r];
        }
    __syncthreads();
    const int growt = rd * 32 + lrow + ((lrow >> 5) * 96);
    const long rowbase = (long)(bm + growt) * N + bn;
    if constexpr (MODE == 1) {
      const unsigned* mw =
          maskbits + bz * sMask + (long)(bm + growt) * (N >> 5) + (bn >> 5);
      const uint4 w0 = *reinterpret_cast<const uint4*>(mw);
      const uint4 w1 = *reinterpret_cast<const uint4*>(mw + 4);
      const unsigned wq[8] = {w0.x, w0.y, w0.z, w0.w, w1.x, w1.y, w1.z, w1.w};
#pragma unroll
      for (int q = 0; q < 8; ++q) {
        const int c4 = (q * 8 + t7) * 4;
        const f32x4 v = *reinterpret_cast<const f32x4*>(&eb[lrow * 256 + c4]);
        const unsigned nib = (wq[q] >> (t7 * 4)) & 0xFu;
        bf16x4 o;
        o[0] = (bf16_t)((nib & 1u) ? 1.f / (1.f + __expf(-v[0])) : 0.f);
        o[1] = (bf16_t)((nib & 2u) ? 1.f / (1.f + __expf(-v[1])) : 0.f);
        o[2] = (bf16_t)((nib & 4u) ? 1.f / (1.f + __expf(-v[2])) : 0.f);
        o[3] = (bf16_t)((nib & 8u) ? 1.f / (1.f + __expf(-v[3])) : 0.f);
        *reinterpret_cast<bf16x4*>((bf16_t*)Cout + bz * sC + rowbase + c4) = o;
      }
    } else {
#pragma unroll
      for (int q = 0; q < 8; ++q) {
        const int c4 = (q * 8 + t7) * 4;
        const f32x4 v = *reinterpret_cast<const f32x4*>(&eb[lrow * 256 + c4]);
        if constexpr (MODE == 0) {
          const f32x4 b4 = *reinterpret_cast<const f32x4*>(bias + bn + c4);
          bf16x4 o;
          o[0] = (bf16_t)(v[0] + b4[0]); o[1] = (bf16_t)(v[1] + b4[1]);
          o[2] = (bf16_t)(v[2] + b4[2]); o[3] = (bf16_t)(v[3] + b4[3]);
          *reinterpret_cast<bf16x4*>((bf16_t*)Cout + bz * sC + rowbase + c4) = o;
        } else {
          *reinterpret_cast<f32x4*>((float*)Cout + bz * sC + rowbase + c4) = v;
        }
      }
    }
  }
}

extern "C" void kernel_launch(void* const* d_in, const int* in_sizes, int n_in,
                              void* d_out, int out_size, void* d_ws, size_t ws_size,
                              hipStream_t stream) {
  const float* queries = (const float*)d_in[0];
  const float* values  = (const float*)d_in[1];
  const int*   mask    = (const int*)d_in[2];
  const float* Wq = (const float*)d_in[3];
  const float* bq = (const float*)d_in[4];
  const float* Wk = (const float*)d_in[5];
  const float* bk = (const float*)d_in[6];
  const float* Wv = (const float*)d_in[7];
  const float* bv = (const float*)d_in[8];

  // B=8, L=2048, D=768. Workspace layout (bytes):
  char* ws = (char*)d_ws;
  bf16_t* qb  = (bf16_t*)(ws + 0);          // queries bf16   25165824
  bf16_t* vb  = (bf16_t*)(ws + 25165824);   // values bf16    25165824
  bf16_t* wqb = (bf16_t*)(ws + 50331648);   // Wq bf16         1179648
  bf16_t* wkb = (bf16_t*)(ws + 51511296);   // Wk bf16         1179648
  bf16_t* wvb = (bf16_t*)(ws + 52690944);   // Wv bf16         1179648
  bf16_t* qp  = (bf16_t*)(ws + 53870592);   // q_proj         25165824
  bf16_t* vp  = (bf16_t*)(ws + 79036416);   // v_proj         25165824
  bf16_t* kp  = (bf16_t*)(ws + 104202240);  // k_proj         25165824
  bf16_t* vpT = (bf16_t*)(ws + 129368064);  // v_proj^T       25165824
  bf16_t* P   = (bf16_t*)(ws + 154533888);  // sigmoid scores 67108864
  unsigned* mbits = (unsigned*)(ws + 221642752);  // 4194304
  // total: 225837056

  // mask pack: 33.55M ints / 32 per thread = 1048576 threads
  mask_pack_kernel<<<4096, 256, 0, stream>>>(mask, mbits);

  // converts
  f32_to_bf16_kernel<<<12288, 256, 0, stream>>>(queries, qb, 3145728);
  f32_to_bf16_kernel<<<12288, 256, 0, stream>>>(values, vb, 3145728);
  f32_to_bf16_kernel<<<576, 256, 0, stream>>>(Wq, wqb, 147456);
  f32_to_bf16_kernel<<<576, 256, 0, stream>>>(Wk, wkb, 147456);
  f32_to_bf16_kernel<<<576, 256, 0, stream>>>(Wv, wvb, 147456);

  const dim3 blk2(512);

  // projections: [16384,768] x W[768,768]^T + b -> bf16
  gemm8p_kernel<0><<<dim3(64, 3, 1), blk2, 0, stream>>>(
      qb, wqb, bq, nullptr, qp, 16384, 768, 768, 0, 0, 0, 0);
  gemm8p_kernel<0><<<dim3(64, 3, 1), blk2, 0, stream>>>(
      vb, wvb, bv, nullptr, vp, 16384, 768, 768, 0, 0, 0, 0);
  // NOTE faithful quirk: k = Linear_k(v_proj)
  gemm8p_kernel<0><<<dim3(64, 3, 1), blk2, 0, stream>>>(
      vp, wkb, bk, nullptr, kp, 16384, 768, 768, 0, 0, 0, 0);

  // v_proj [b][2048][768] -> v_projT [b][768][2048]
  transpose_bf16_kernel<<<dim3(32, 12, 8), 256, 0, stream>>>(vp, vpT, 2048, 768);

  // P = sigmoid(mask(q k^T)) : per batch [2048,2048], K=768; mask = packed bits
  gemm8p_kernel<1><<<dim3(8, 8, 8), blk2, 0, stream>>>(
      qp, kp, nullptr, mbits, P, 2048, 2048, 768,
      (long)2048 * 768, (long)2048 * 768, (long)2048 * 2048, (long)2048 * 64);

  // context = P v : per batch [2048,768], K=2048, fp32 out
  gemm8p_kernel<2><<<dim3(8, 3, 8), blk2, 0, stream>>>(
      P, vpT, nullptr, nullptr, d_out, 2048, 768, 2048,
      (long)2048 * 2048, (long)768 * 2048, (long)2048 * 768, 0);
}

// Round 7
// 292.852 us; speedup vs baseline: 1.7628x; 1.7628x over previous
//
#include <hip/hip_runtime.h>
#include <hip/hip_bf16.h>

typedef __bf16 bf16_t;
typedef __bf16 bf16x8 __attribute__((ext_vector_type(8)));
typedef __bf16 bf16x4 __attribute__((ext_vector_type(4)));
typedef float  f32x4  __attribute__((ext_vector_type(4)));

#define LDS_DST(p) ((__attribute__((address_space(3))) void*)(p))
#define GLB_SRC(p) ((const __attribute__((address_space(1))) void*)(p))

#define SBAR()   asm volatile("s_barrier" ::: "memory")
#define WVM8()   asm volatile("s_waitcnt vmcnt(8)" ::: "memory")
#define WVM4()   asm volatile("s_waitcnt vmcnt(4)" ::: "memory")
#define WVM0()   asm volatile("s_waitcnt vmcnt(0)" ::: "memory")
#define SP1()    __builtin_amdgcn_s_setprio(1)
#define SP0()    __builtin_amdgcn_s_setprio(0)

// ---------------- fp32 -> bf16 convert ----------------
__global__ void __launch_bounds__(256)
f32_to_bf16_kernel(const float* __restrict__ in, bf16_t* __restrict__ out, int n4) {
  int i = blockIdx.x * 256 + threadIdx.x;
  if (i < n4) {
    const float4 v = reinterpret_cast<const float4*>(in)[i];
    bf16x4 o;
    o[0] = (bf16_t)v.x; o[1] = (bf16_t)v.y; o[2] = (bf16_t)v.z; o[3] = (bf16_t)v.w;
    reinterpret_cast<bf16x4*>(out)[i] = o;
  }
}

// -------- mask int32 -> bitmask; bit (32i + b) = mask[32i + b] --------
__global__ void __launch_bounds__(256)
mask_pack_kernel(const int* __restrict__ mask, unsigned* __restrict__ bits) {
  const long i = (long)blockIdx.x * 256 + threadIdx.x;
  const int4* m4 = reinterpret_cast<const int4*>(mask + i * 32);
  unsigned w = 0;
#pragma unroll
  for (int j = 0; j < 8; ++j) {
    const int4 v = m4[j];
    w |= (v.x != 0 ? 1u : 0u) << (j * 4);
    w |= (v.y != 0 ? 2u : 0u) << (j * 4);
    w |= (v.z != 0 ? 4u : 0u) << (j * 4);
    w |= (v.w != 0 ? 8u : 0u) << (j * 4);
  }
  bits[i] = w;
}

// ---------------- bf16 transpose: in [z][R][C] -> out [z][C][R] ----------------
__global__ void __launch_bounds__(256)
transpose_bf16_kernel(const bf16_t* __restrict__ in, bf16_t* __restrict__ out,
                      int R, int C) {
  __shared__ bf16_t tile[64][72];
  const long base = (long)blockIdx.z * R * C;
  const bf16_t* ib = in + base;
  bf16_t* ob = out + base;
  const int r0 = blockIdx.x * 64, c0 = blockIdx.y * 64;
  const int tid = threadIdx.x;
  const int rr = tid >> 3, cg = tid & 7;
#pragma unroll
  for (int p = 0; p < 2; ++p) {
    int row = p * 32 + rr;
    bf16x8 v = *reinterpret_cast<const bf16x8*>(ib + (long)(r0 + row) * C + c0 + cg * 8);
    *reinterpret_cast<bf16x8*>(&tile[row][cg * 8]) = v;
  }
  __syncthreads();
#pragma unroll
  for (int p = 0; p < 2; ++p) {
    int c = p * 32 + rr;
    bf16x8 v;
#pragma unroll
    for (int i = 0; i < 8; ++i) v[i] = tile[cg * 8 + i][c];
    *reinterpret_cast<bf16x8*>(ob + (long)(c0 + c) * R + r0 + cg * 8) = v;
  }
}

// ========== 256x256 GEMM, 2 merged phases per K-tile, counted vmcnt ==========
// REGISTER BUDGET (hard limit, learned R6): acc 128 AGPR + <=16 live frags
// (afX[8], bfB[4], bf0[4] = 64 VGPR) + addressing = 256 cap at (512,2).
// Any schedule edit must NOT add live fragments (R6: +afY[8] -> 283MB spill).
//
// Per tile t (slot so = t%2, sn = so^1):  [entering: afX=A0(t), bf0=B0(t)]
//  P_a: read B1(t)->bfB; stage A0(t+2),B0(t+2)->so;
//       q00(afX,bf0); q01(afX,bfB); read A1(t)->afX;        vmcnt(8); SBAR c1
//  P_b: q11(afX,bfB); q10(afX,bf0);
//       read A0(t+1)->afX, B0(t+1)->bf0 (from sn);
//       stage B1(t+2),A1(t+2)->so;                          vmcnt(8); SBAR c2
// ds_reads/tile: A 16 + B 8 = 24 (B0 held across tile, no re-read).
// Hazards (stage overwrites region, >=1 barrier after last read):
//   A0(t+2)@Pa(t) vs read A0(t+1)@Pb(t-1): c2(t-1).  B0: same.
//   B1(t+2)@Pb(t) vs read B1(t)@Pa(t): c1(t).  A1: same.
// vmcnt(8) at instr granularity (4 gload instrs/phase, queue=12 at each bar):
//   c1(t): oldest 4 = A0/B0(t+1) confirmed before Pb(t) reads them.
//   c2(t): oldest 4 = B1/A1(t+1) confirmed before Pa(t+1) reads them.
// Prologue stages t0(8)+A0/B0(1)(4)+B1/A1(1)(4); WVM8 = t0 landed.
// Drain: c1(NT-2)=vmcnt(4) [A0/B0(NT-1)], c2(NT-2)=vmcnt(0) [B1/A1(NT-1)].

__device__ __forceinline__ void read_A(const char* smem, int off, bf16x8 (&af)[8], int xk0) {
#pragma unroll
  for (int mf = 0; mf < 4; ++mf)
#pragma unroll
    for (int kk = 0; kk < 2; ++kk)
      af[mf * 2 + kk] = *reinterpret_cast<const bf16x8*>(
          smem + off + mf * 2048 + (kk ? (xk0 ^ 64) : xk0));
}

__device__ __forceinline__ void read_B(const char* smem, int off, bf16x8 (&bf_)[4], int xk0) {
#pragma unroll
  for (int nf = 0; nf < 2; ++nf)
#pragma unroll
    for (int kk = 0; kk < 2; ++kk)
      bf_[nf * 2 + kk] = *reinterpret_cast<const bf16x8*>(
          smem + off + nf * 2048 + (kk ? (xk0 ^ 64) : xk0));
}

template <int MH, int NH>
__device__ __forceinline__ void mfma_q(const bf16x8 (&af)[8], const bf16x8 (&bf_)[4],
                                       f32x4 (&acc)[8][4]) {
#pragma unroll
  for (int mf = 0; mf < 4; ++mf)
#pragma unroll
    for (int nf = 0; nf < 2; ++nf)
#pragma unroll
      for (int kk = 0; kk < 2; ++kk)
        acc[MH * 4 + mf][NH * 2 + nf] = __builtin_amdgcn_mfma_f32_16x16x32_bf16(
            af[mf * 2 + kk], bf_[nf * 2 + kk], acc[MH * 4 + mf][NH * 2 + nf], 0, 0, 0);
}

#define STAGE_A(slot, mh, kt) do {                                            \
  _Pragma("unroll") for (int j_ = 0; j_ < 2; ++j_)                            \
    __builtin_amdgcn_global_load_lds(                                         \
        GLB_SRC(pA + (long)(j_ * 128 + (mh) * 64) * K + (kt)),                \
        LDS_DST(smem + (slot) * 65536 + (arow0 + j_ * 128 + (mh) * 64) * 128),\
        16, 0, 0);                                                            \
} while (0)

#define STAGE_B(slot, nh, kt) do {                                            \
  _Pragma("unroll") for (int j_ = 0; j_ < 2; ++j_)                            \
    __builtin_amdgcn_global_load_lds(                                         \
        GLB_SRC(pB + (long)(j_ * 128 + (nh) * 32) * K + (kt)),                \
        LDS_DST(smem + (slot) * 65536 + 32768 +                               \
                (brow0 + j_ * 128 + (nh) * 32) * 128),                        \
        16, 0, 0);                                                            \
} while (0)

// MODE 0: bf16 out = acc + bias[n];  MODE 1: bf16 out = maskbit?sigmoid(acc):0;
// MODE 2: f32 out = acc
template <int MODE>
__global__ void __launch_bounds__(512, 2)
gemm8p_kernel(const bf16_t* __restrict__ A, const bf16_t* __restrict__ B,
              const float* __restrict__ bias, const unsigned* __restrict__ maskbits,
              void* __restrict__ Cout, int M, int N, int K,
              long sA, long sB, long sC, long sMask) {
  __shared__ __align__(1024) char smem[131072];
  const int bz = blockIdx.z;
  const bf16_t* Ab = A + bz * sA;
  const bf16_t* Bb = B + bz * sB;
  const int bm = blockIdx.x * 256, bn = blockIdx.y * 256;
  const int tid = threadIdx.x;
  const int wave = tid >> 6, lane = tid & 63;
  const int wr = wave >> 2, wc = wave & 3;
  const int l15 = lane & 15, lg = lane >> 4;
  const int xk0 = (lg * 16) ^ ((lane & 7) << 4);
  const int NT = K >> 6;

  // staging bases
  const int lr = lane >> 3;
  const int cgs = ((lane & 7) ^ lr) * 8;
  const int arow0 = wave * 8;
  const int brow0 = (wave >> 2) * 64 + (wave & 3) * 8;
  const bf16_t* pA = Ab + (long)(bm + arow0 + lr) * K + cgs;
  const bf16_t* pB = Bb + (long)(bn + brow0 + lr) * K + cgs;

  // ds_read base offsets
  const int aoff = wr * 16384 + l15 * 128;          // + slot*65536 + mh*8192
  const int boff = 32768 + wc * 8192 + l15 * 128;   // + slot*65536 + nh*4096

  f32x4 acc[8][4] = {};
  bf16x8 afX[8], bfB[4], bf0[4];

  // ---- prologue: t0 full (8 instrs), then A0/B0(1) (4), B1/A1(1) (4) ----
  STAGE_A(0, 0, 0); STAGE_B(0, 0, 0); STAGE_B(0, 1, 0); STAGE_A(0, 1, 0);
  STAGE_A(1, 0, 64); STAGE_B(1, 0, 64);
  STAGE_B(1, 1, 64); STAGE_A(1, 1, 64);
  WVM8();   // tile0's 8 instrs landed
  SBAR();
  read_A(smem, aoff + 0, afX, xk0);   // A0(t0)
  read_B(smem, boff + 0, bf0, xk0);   // B0(t0)

  int slot = 0;
  for (int t = 0; t + 2 < NT; ++t) {
    const int so = slot * 65536, sn = (slot ^ 1) * 65536;
    const int k2 = (t + 2) << 6;
    // ---- P_a ----
    read_B(smem, so + boff + 4096, bfB, xk0);        // B1(t)
    STAGE_A(slot, 0, k2); STAGE_B(slot, 0, k2);      // A0(t+2), B0(t+2)
    SP1(); mfma_q<0, 0>(afX, bf0, acc); SP0();
    SP1(); mfma_q<0, 1>(afX, bfB, acc); SP0();
    read_A(smem, so + aoff + 8192, afX, xk0);        // A1(t)
    WVM8(); SBAR();                                  // c1
    // ---- P_b ----
    SP1(); mfma_q<1, 1>(afX, bfB, acc); SP0();
    SP1(); mfma_q<1, 0>(afX, bf0, acc); SP0();
    read_A(smem, sn + aoff + 0, afX, xk0);           // A0(t+1)
    read_B(smem, sn + boff + 0, bf0, xk0);           // B0(t+1)
    STAGE_B(slot, 1, k2); STAGE_A(slot, 1, k2);      // B1(t+2), A1(t+2)
    WVM8(); SBAR();                                  // c2
    slot ^= 1;
  }

  // ---- drain: tiles NT-2 (so), NT-1 (sn); no staging ----
  {
    const int so = slot * 65536, sn = (slot ^ 1) * 65536;
    read_B(smem, so + boff + 4096, bfB, xk0);        // B1(NT-2)
    SP1(); mfma_q<0, 0>(afX, bf0, acc); SP0();
    SP1(); mfma_q<0, 1>(afX, bfB, acc); SP0();
    read_A(smem, so + aoff + 8192, afX, xk0);        // A1(NT-2)
    WVM4(); SBAR();
    SP1(); mfma_q<1, 1>(afX, bfB, acc); SP0();
    SP1(); mfma_q<1, 0>(afX, bf0, acc); SP0();
    read_A(smem, sn + aoff + 0, afX, xk0);           // A0(NT-1)
    read_B(smem, sn + boff + 0, bf0, xk0);           // B0(NT-1)
    WVM0(); SBAR();
    // last tile
    read_B(smem, sn + boff + 4096, bfB, xk0);        // B1(NT-1)
    SP1(); mfma_q<0, 0>(afX, bf0, acc); SP0();
    SP1(); mfma_q<0, 1>(afX, bfB, acc); SP0();
    read_A(smem, sn + aoff + 8192, afX, xk0);        // A1(NT-1)
    SP1(); mfma_q<1, 1>(afX, bfB, acc); SP0();
    SP1(); mfma_q<1, 0>(afX, bf0, acc); SP0();
  }

  // ---- C-write: 4 rounds of 64-row LDS rearrange, coalesced I/O ----
  // (fully unrolled: acc indices must stay compile-time -- rule #20)
  float* eb = (float*)smem;
  const int lrow = tid >> 3, t7 = tid & 7;
#pragma unroll
  for (int rd = 0; rd < 4; ++rd) {
    __syncthreads();
#pragma unroll
    for (int fi = 0; fi < 2; ++fi)
#pragma unroll
      for (int nf = 0; nf < 4; ++nf)
#pragma unroll
        for (int r = 0; r < 4; ++r) {
          const int lr2 = wr * 32 + fi * 16 + lg * 4 + r;
          eb[lr2 * 256 + wc * 64 + nf * 16 + l15] = acc[rd * 2 + fi][nf][r];
        }
    __syncthreads();
    const int growt = rd * 32 + lrow + ((lrow >> 5) * 96);
    const long rowbase = (long)(bm + growt) * N + bn;
    if constexpr (MODE == 1) {
      const unsigned* mw =
          maskbits + bz * sMask + (long)(bm + growt) * (N >> 5) + (bn >> 5);
      const uint4 w0 = *reinterpret_cast<const uint4*>(mw);
      const uint4 w1 = *reinterpret_cast<const uint4*>(mw + 4);
      const unsigned wq[8] = {w0.x, w0.y, w0.z, w0.w, w1.x, w1.y, w1.z, w1.w};
#pragma unroll
      for (int q = 0; q < 8; ++q) {
        const int c4 = (q * 8 + t7) * 4;
        const f32x4 v = *reinterpret_cast<const f32x4*>(&eb[lrow * 256 + c4]);
        const unsigned nib = (wq[q] >> (t7 * 4)) & 0xFu;
        bf16x4 o;
        o[0] = (bf16_t)((nib & 1u) ? 1.f / (1.f + __expf(-v[0])) : 0.f);
        o[1] = (bf16_t)((nib & 2u) ? 1.f / (1.f + __expf(-v[1])) : 0.f);
        o[2] = (bf16_t)((nib & 4u) ? 1.f / (1.f + __expf(-v[2])) : 0.f);
        o[3] = (bf16_t)((nib & 8u) ? 1.f / (1.f + __expf(-v[3])) : 0.f);
        *reinterpret_cast<bf16x4*>((bf16_t*)Cout + bz * sC + rowbase + c4) = o;
      }
    } else {
#pragma unroll
      for (int q = 0; q < 8; ++q) {
        const int c4 = (q * 8 + t7) * 4;
        const f32x4 v = *reinterpret_cast<const f32x4*>(&eb[lrow * 256 + c4]);
        if constexpr (MODE == 0) {
          const f32x4 b4 = *reinterpret_cast<const f32x4*>(bias + bn + c4);
          bf16x4 o;
          o[0] = (bf16_t)(v[0] + b4[0]); o[1] = (bf16_t)(v[1] + b4[1]);
          o[2] = (bf16_t)(v[2] + b4[2]); o[3] = (bf16_t)(v[3] + b4[3]);
          *reinterpret_cast<bf16x4*>((bf16_t*)Cout + bz * sC + rowbase + c4) = o;
        } else {
          *reinterpret_cast<f32x4*>((float*)Cout + bz * sC + rowbase + c4) = v;
        }
      }
    }
  }
}

extern "C" void kernel_launch(void* const* d_in, const int* in_sizes, int n_in,
                              void* d_out, int out_size, void* d_ws, size_t ws_size,
                              hipStream_t stream) {
  const float* queries = (const float*)d_in[0];
  const float* values  = (const float*)d_in[1];
  const int*   mask    = (const int*)d_in[2];
  const float* Wq = (const float*)d_in[3];
  const float* bq = (const float*)d_in[4];
  const float* Wk = (const float*)d_in[5];
  const float* bk = (const float*)d_in[6];
  const float* Wv = (const float*)d_in[7];
  const float* bv = (const float*)d_in[8];

  // B=8, L=2048, D=768. Workspace layout (bytes):
  char* ws = (char*)d_ws;
  bf16_t* qb  = (bf16_t*)(ws + 0);          // queries bf16   25165824
  bf16_t* vb  = (bf16_t*)(ws + 25165824);   // values bf16    25165824
  bf16_t* wqb = (bf16_t*)(ws + 50331648);   // Wq bf16         1179648
  bf16_t* wkb = (bf16_t*)(ws + 51511296);   // Wk bf16         1179648
  bf16_t* wvb = (bf16_t*)(ws + 52690944);   // Wv bf16         1179648
  bf16_t* qp  = (bf16_t*)(ws + 53870592);   // q_proj         25165824
  bf16_t* vp  = (bf16_t*)(ws + 79036416);   // v_proj         25165824
  bf16_t* kp  = (bf16_t*)(ws + 104202240);  // k_proj         25165824
  bf16_t* vpT = (bf16_t*)(ws + 129368064);  // v_proj^T       25165824
  bf16_t* P   = (bf16_t*)(ws + 154533888);  // sigmoid scores 67108864
  unsigned* mbits = (unsigned*)(ws + 221642752);  // 4194304
  // total: 225837056

  // mask pack: 33.55M ints / 32 per thread
  mask_pack_kernel<<<4096, 256, 0, stream>>>(mask, mbits);

  // converts
  f32_to_bf16_kernel<<<12288, 256, 0, stream>>>(queries, qb, 3145728);
  f32_to_bf16_kernel<<<12288, 256, 0, stream>>>(values, vb, 3145728);
  f32_to_bf16_kernel<<<576, 256, 0, stream>>>(Wq, wqb, 147456);
  f32_to_bf16_kernel<<<576, 256, 0, stream>>>(Wk, wkb, 147456);
  f32_to_bf16_kernel<<<576, 256, 0, stream>>>(Wv, wvb, 147456);

  const dim3 blk2(512);

  // projections: [16384,768] x W[768,768]^T + b -> bf16
  gemm8p_kernel<0><<<dim3(64, 3, 1), blk2, 0, stream>>>(
      qb, wqb, bq, nullptr, qp, 16384, 768, 768, 0, 0, 0, 0);
  gemm8p_kernel<0><<<dim3(64, 3, 1), blk2, 0, stream>>>(
      vb, wvb, bv, nullptr, vp, 16384, 768, 768, 0, 0, 0, 0);
  // NOTE faithful quirk: k = Linear_k(v_proj)
  gemm8p_kernel<0><<<dim3(64, 3, 1), blk2, 0, stream>>>(
      vp, wkb, bk, nullptr, kp, 16384, 768, 768, 0, 0, 0, 0);

  // v_proj [b][2048][768] -> v_projT [b][768][2048]
  transpose_bf16_kernel<<<dim3(32, 12, 8), 256, 0, stream>>>(vp, vpT, 2048, 768);

  // P = sigmoid(mask(q k^T)) : per batch [2048,2048], K=768; mask = packed bits
  gemm8p_kernel<1><<<dim3(8, 8, 8), blk2, 0, stream>>>(
      qp, kp, nullptr, mbits, P, 2048, 2048, 768,
      (long)2048 * 768, (long)2048 * 768, (long)2048 * 2048, (long)2048 * 64);

  // context = P v : per batch [2048,768], K=2048, fp32 out
  gemm8p_kernel<2><<<dim3(8, 3, 8), blk2, 0, stream>>>(
      P, vpT, nullptr, nullptr, d_out, 2048, 768, 2048,
      (long)2048 * 2048, (long)768 * 2048, (long)2048 * 768, 0);
}

// Round 8
// 271.768 us; speedup vs baseline: 1.8996x; 1.0776x over previous
//
#include <hip/hip_runtime.h>
#include <hip/hip_bf16.h>

typedef __bf16 bf16_t;
typedef __bf16 bf16x8 __attribute__((ext_vector_type(8)));
typedef __bf16 bf16x4 __attribute__((ext_vector_type(4)));
typedef float  f32x4  __attribute__((ext_vector_type(4)));

#define LDS_DST(p) ((__attribute__((address_space(3))) void*)(p))
#define GLB_SRC(p) ((const __attribute__((address_space(1))) void*)(p))

#define SBAR()   asm volatile("s_barrier" ::: "memory")
#define WVM8()   asm volatile("s_waitcnt vmcnt(8)" ::: "memory")
#define WVM4()   asm volatile("s_waitcnt vmcnt(4)" ::: "memory")
#define WVM0()   asm volatile("s_waitcnt vmcnt(0)" ::: "memory")
#define SP1()    __builtin_amdgcn_s_setprio(1)
#define SP0()    __builtin_amdgcn_s_setprio(0)

// ---------------- fp32 -> bf16 converts (z selects source) ----------------
__global__ void __launch_bounds__(256)
conv2_kernel(const float* __restrict__ a, const float* __restrict__ b,
             bf16_t* __restrict__ oa, bf16_t* __restrict__ ob, int n4) {
  const float* in = blockIdx.z ? b : a;
  bf16_t* out = blockIdx.z ? ob : oa;
  int i = blockIdx.x * 256 + threadIdx.x;
  if (i < n4) {
    const float4 v = reinterpret_cast<const float4*>(in)[i];
    bf16x4 o;
    o[0] = (bf16_t)v.x; o[1] = (bf16_t)v.y; o[2] = (bf16_t)v.z; o[3] = (bf16_t)v.w;
    reinterpret_cast<bf16x4*>(out)[i] = o;
  }
}

__global__ void __launch_bounds__(256)
conv3_kernel(const float* __restrict__ a, const float* __restrict__ b,
             const float* __restrict__ c, bf16_t* __restrict__ oa,
             bf16_t* __restrict__ ob, bf16_t* __restrict__ oc, int n4) {
  const float* in = blockIdx.z == 0 ? a : (blockIdx.z == 1 ? b : c);
  bf16_t* out = blockIdx.z == 0 ? oa : (blockIdx.z == 1 ? ob : oc);
  int i = blockIdx.x * 256 + threadIdx.x;
  if (i < n4) {
    const float4 v = reinterpret_cast<const float4*>(in)[i];
    bf16x4 o;
    o[0] = (bf16_t)v.x; o[1] = (bf16_t)v.y; o[2] = (bf16_t)v.z; o[3] = (bf16_t)v.w;
    reinterpret_cast<bf16x4*>(out)[i] = o;
  }
}

// -------- mask int32 -> bitmask via ballot (coalesced 4B/lane loads) --------
// u64 word k covers ints [64k, 64k+64) in linear order (ballot bit l = lane l).
__global__ void __launch_bounds__(256)
mask_pack_kernel(const int* __restrict__ mask, unsigned long long* __restrict__ bits) {
  const long wid = (((long)blockIdx.x * 256 + threadIdx.x) >> 6);
  const int lane = threadIdx.x & 63;
  const long base = wid * 512;
  unsigned long long b[8];
#pragma unroll
  for (int i = 0; i < 8; ++i) {
    const int m = mask[base + i * 64 + lane];
    b[i] = __ballot(m != 0);
  }
  if (lane == 0) {
    unsigned long long* o = bits + wid * 8;
#pragma unroll
    for (int i = 0; i < 8; ++i) o[i] = b[i];
  }
}

// ---------------- bf16 transpose: in [z][R][C] -> out [z][C][R] ----------------
__global__ void __launch_bounds__(256)
transpose_bf16_kernel(const bf16_t* __restrict__ in, bf16_t* __restrict__ out,
                      int R, int C) {
  __shared__ bf16_t tile[64][72];
  const long base = (long)blockIdx.z * R * C;
  const bf16_t* ib = in + base;
  bf16_t* ob = out + base;
  const int r0 = blockIdx.x * 64, c0 = blockIdx.y * 64;
  const int tid = threadIdx.x;
  const int rr = tid >> 3, cg = tid & 7;
#pragma unroll
  for (int p = 0; p < 2; ++p) {
    int row = p * 32 + rr;
    bf16x8 v = *reinterpret_cast<const bf16x8*>(ib + (long)(r0 + row) * C + c0 + cg * 8);
    *reinterpret_cast<bf16x8*>(&tile[row][cg * 8]) = v;
  }
  __syncthreads();
#pragma unroll
  for (int p = 0; p < 2; ++p) {
    int c = p * 32 + rr;
    bf16x8 v;
#pragma unroll
    for (int i = 0; i < 8; ++i) v[i] = tile[cg * 8 + i][c];
    *reinterpret_cast<bf16x8*>(ob + (long)(c0 + c) * R + r0 + cg * 8) = v;
  }
}

// ========== 256x256 GEMM, 2 merged phases per K-tile, counted vmcnt ==========
// (schedule unchanged from R7 -- see R7 hazard map in history; only additions:
//  bijective XCD swizzle of the flat block id, MODE0 alt-pointer batch (z=1),
//  rcpf sigmoid.)
// REGISTER BUDGET (hard limit, learned R6): acc 128 AGPR + <=16 live frags.

__device__ __forceinline__ void read_A(const char* smem, int off, bf16x8 (&af)[8], int xk0) {
#pragma unroll
  for (int mf = 0; mf < 4; ++mf)
#pragma unroll
    for (int kk = 0; kk < 2; ++kk)
      af[mf * 2 + kk] = *reinterpret_cast<const bf16x8*>(
          smem + off + mf * 2048 + (kk ? (xk0 ^ 64) : xk0));
}

__device__ __forceinline__ void read_B(const char* smem, int off, bf16x8 (&bf_)[4], int xk0) {
#pragma unroll
  for (int nf = 0; nf < 2; ++nf)
#pragma unroll
    for (int kk = 0; kk < 2; ++kk)
      bf_[nf * 2 + kk] = *reinterpret_cast<const bf16x8*>(
          smem + off + nf * 2048 + (kk ? (xk0 ^ 64) : xk0));
}

template <int MH, int NH>
__device__ __forceinline__ void mfma_q(const bf16x8 (&af)[8], const bf16x8 (&bf_)[4],
                                       f32x4 (&acc)[8][4]) {
#pragma unroll
  for (int mf = 0; mf < 4; ++mf)
#pragma unroll
    for (int nf = 0; nf < 2; ++nf)
#pragma unroll
      for (int kk = 0; kk < 2; ++kk)
        acc[MH * 4 + mf][NH * 2 + nf] = __builtin_amdgcn_mfma_f32_16x16x32_bf16(
            af[mf * 2 + kk], bf_[nf * 2 + kk], acc[MH * 4 + mf][NH * 2 + nf], 0, 0, 0);
}

#define STAGE_A(slot, mh, kt) do {                                            \
  _Pragma("unroll") for (int j_ = 0; j_ < 2; ++j_)                            \
    __builtin_amdgcn_global_load_lds(                                         \
        GLB_SRC(pA + (long)(j_ * 128 + (mh) * 64) * K + (kt)),                \
        LDS_DST(smem + (slot) * 65536 + (arow0 + j_ * 128 + (mh) * 64) * 128),\
        16, 0, 0);                                                            \
} while (0)

#define STAGE_B(slot, nh, kt) do {                                            \
  _Pragma("unroll") for (int j_ = 0; j_ < 2; ++j_)                            \
    __builtin_amdgcn_global_load_lds(                                         \
        GLB_SRC(pB + (long)(j_ * 128 + (nh) * 32) * K + (kt)),                \
        LDS_DST(smem + (slot) * 65536 + 32768 +                               \
                (brow0 + j_ * 128 + (nh) * 32) * 128),                        \
        16, 0, 0);                                                            \
} while (0)

// MODE 0: bf16 out = acc + bias[n] (z=1 uses alt pointer set A2/B2/bias2/C2)
// MODE 1: bf16 out = maskbit ? sigmoid(acc) : 0;  MODE 2: f32 out = acc
template <int MODE>
__global__ void __launch_bounds__(512, 2)
gemm8p_kernel(const bf16_t* __restrict__ A, const bf16_t* __restrict__ B,
              const float* __restrict__ bias, const unsigned* __restrict__ maskbits,
              void* __restrict__ Cout, int M, int N, int K,
              long sA, long sB, long sC, long sMask,
              const bf16_t* __restrict__ A2, const bf16_t* __restrict__ B2,
              const float* __restrict__ bias2, void* __restrict__ C2) {
  __shared__ __align__(1024) char smem[131072];

  // ---- bijective XCD swizzle (m204): chunk the flat id so each XCD gets a
  // contiguous run (QK^T/PV: one batch per XCD -> panels L2-resident).
  const int gx = gridDim.x, gy = gridDim.y;
  int flat = blockIdx.x + gx * (blockIdx.y + gy * blockIdx.z);
  const int nwg = gx * gy * (int)gridDim.z;
  const int q8 = nwg >> 3, r8 = nwg & 7;
  const int xcd = flat & 7, idx = flat >> 3;
  flat = (xcd < r8 ? xcd * (q8 + 1) : r8 * (q8 + 1) + (xcd - r8) * q8) + idx;
  const int bxi = flat % gx; flat /= gx;
  const int byi = flat % gy;
  const int bz  = flat / gy;

  const bf16_t* Ab; const bf16_t* Bb;
  const float* biasp = bias; void* Cp = Cout;
  if constexpr (MODE == 0) {
    if (bz) { Ab = A2; Bb = B2; biasp = bias2; Cp = C2; }
    else    { Ab = A;  Bb = B; }
  } else {
    Ab = A + bz * sA; Bb = B + bz * sB;
  }
  const int bm = bxi * 256, bn = byi * 256;
  const int tid = threadIdx.x;
  const int wave = tid >> 6, lane = tid & 63;
  const int wr = wave >> 2, wc = wave & 3;
  const int l15 = lane & 15, lg = lane >> 4;
  const int xk0 = (lg * 16) ^ ((lane & 7) << 4);
  const int NT = K >> 6;

  // staging bases
  const int lr = lane >> 3;
  const int cgs = ((lane & 7) ^ lr) * 8;
  const int arow0 = wave * 8;
  const int brow0 = (wave >> 2) * 64 + (wave & 3) * 8;
  const bf16_t* pA = Ab + (long)(bm + arow0 + lr) * K + cgs;
  const bf16_t* pB = Bb + (long)(bn + brow0 + lr) * K + cgs;

  // ds_read base offsets
  const int aoff = wr * 16384 + l15 * 128;          // + slot*65536 + mh*8192
  const int boff = 32768 + wc * 8192 + l15 * 128;   // + slot*65536 + nh*4096

  f32x4 acc[8][4] = {};
  bf16x8 afX[8], bfB[4], bf0[4];

  // ---- prologue: t0 full (8 instrs), then A0/B0(1) (4), B1/A1(1) (4) ----
  STAGE_A(0, 0, 0); STAGE_B(0, 0, 0); STAGE_B(0, 1, 0); STAGE_A(0, 1, 0);
  STAGE_A(1, 0, 64); STAGE_B(1, 0, 64);
  STAGE_B(1, 1, 64); STAGE_A(1, 1, 64);
  WVM8();   // tile0's 8 instrs landed
  SBAR();
  read_A(smem, aoff + 0, afX, xk0);   // A0(t0)
  read_B(smem, boff + 0, bf0, xk0);   // B0(t0)

  int slot = 0;
  for (int t = 0; t + 2 < NT; ++t) {
    const int so = slot * 65536, sn = (slot ^ 1) * 65536;
    const int k2 = (t + 2) << 6;
    // ---- P_a ----
    read_B(smem, so + boff + 4096, bfB, xk0);        // B1(t)
    STAGE_A(slot, 0, k2); STAGE_B(slot, 0, k2);      // A0(t+2), B0(t+2)
    SP1(); mfma_q<0, 0>(afX, bf0, acc); SP0();
    SP1(); mfma_q<0, 1>(afX, bfB, acc); SP0();
    read_A(smem, so + aoff + 8192, afX, xk0);        // A1(t)
    WVM8(); SBAR();                                  // c1
    // ---- P_b ----
    SP1(); mfma_q<1, 1>(afX, bfB, acc); SP0();
    SP1(); mfma_q<1, 0>(afX, bf0, acc); SP0();
    read_A(smem, sn + aoff + 0, afX, xk0);           // A0(t+1)
    read_B(smem, sn + boff + 0, bf0, xk0);           // B0(t+1)
    STAGE_B(slot, 1, k2); STAGE_A(slot, 1, k2);      // B1(t+2), A1(t+2)
    WVM8(); SBAR();                                  // c2
    slot ^= 1;
  }

  // ---- drain: tiles NT-2 (so), NT-1 (sn); no staging ----
  {
    const int so = slot * 65536, sn = (slot ^ 1) * 65536;
    read_B(smem, so + boff + 4096, bfB, xk0);        // B1(NT-2)
    SP1(); mfma_q<0, 0>(afX, bf0, acc); SP0();
    SP1(); mfma_q<0, 1>(afX, bfB, acc); SP0();
    read_A(smem, so + aoff + 8192, afX, xk0);        // A1(NT-2)
    WVM4(); SBAR();
    SP1(); mfma_q<1, 1>(afX, bfB, acc); SP0();
    SP1(); mfma_q<1, 0>(afX, bf0, acc); SP0();
    read_A(smem, sn + aoff + 0, afX, xk0);           // A0(NT-1)
    read_B(smem, sn + boff + 0, bf0, xk0);           // B0(NT-1)
    WVM0(); SBAR();
    // last tile
    read_B(smem, sn + boff + 4096, bfB, xk0);        // B1(NT-1)
    SP1(); mfma_q<0, 0>(afX, bf0, acc); SP0();
    SP1(); mfma_q<0, 1>(afX, bfB, acc); SP0();
    read_A(smem, sn + aoff + 8192, afX, xk0);        // A1(NT-1)
    SP1(); mfma_q<1, 1>(afX, bfB, acc); SP0();
    SP1(); mfma_q<1, 0>(afX, bf0, acc); SP0();
  }

  // ---- C-write: 4 rounds of 64-row LDS rearrange, coalesced I/O ----
  // (fully unrolled: acc indices must stay compile-time -- rule #20)
  float* eb = (float*)smem;
  const int lrow = tid >> 3, t7 = tid & 7;
#pragma unroll
  for (int rd = 0; rd < 4; ++rd) {
    __syncthreads();
#pragma unroll
    for (int fi = 0; fi < 2; ++fi)
#pragma unroll
      for (int nf = 0; nf < 4; ++nf)
#pragma unroll
        for (int r = 0; r < 4; ++r) {
          const int lr2 = wr * 32 + fi * 16 + lg * 4 + r;
          eb[lr2 * 256 + wc * 64 + nf * 16 + l15] = acc[rd * 2 + fi][nf][r];
        }
    __syncthreads();
    const int growt = rd * 32 + lrow + ((lrow >> 5) * 96);
    const long rowbase = (long)(bm + growt) * N + bn;
    if constexpr (MODE == 1) {
      const unsigned* mw =
          maskbits + bz * sMask + (long)(bm + growt) * (N >> 5) + (bn >> 5);
      const uint4 w0 = *reinterpret_cast<const uint4*>(mw);
      const uint4 w1 = *reinterpret_cast<const uint4*>(mw + 4);
      const unsigned wq[8] = {w0.x, w0.y, w0.z, w0.w, w1.x, w1.y, w1.z, w1.w};
#pragma unroll
      for (int q = 0; q < 8; ++q) {
        const int c4 = (q * 8 + t7) * 4;
        const f32x4 v = *reinterpret_cast<const f32x4*>(&eb[lrow * 256 + c4]);
        const unsigned nib = (wq[q] >> (t7 * 4)) & 0xFu;
        bf16x4 o;
        o[0] = (bf16_t)((nib & 1u) ? __builtin_amdgcn_rcpf(1.f + __expf(-v[0])) : 0.f);
        o[1] = (bf16_t)((nib & 2u) ? __builtin_amdgcn_rcpf(1.f + __expf(-v[1])) : 0.f);
        o[2] = (bf16_t)((nib & 4u) ? __builtin_amdgcn_rcpf(1.f + __expf(-v[2])) : 0.f);
        o[3] = (bf16_t)((nib & 8u) ? __builtin_amdgcn_rcpf(1.f + __expf(-v[3])) : 0.f);
        *reinterpret_cast<bf16x4*>((bf16_t*)Cp + bz * sC + rowbase + c4) = o;
      }
    } else {
#pragma unroll
      for (int q = 0; q < 8; ++q) {
        const int c4 = (q * 8 + t7) * 4;
        const f32x4 v = *reinterpret_cast<const f32x4*>(&eb[lrow * 256 + c4]);
        if constexpr (MODE == 0) {
          const f32x4 b4 = *reinterpret_cast<const f32x4*>(biasp + bn + c4);
          bf16x4 o;
          o[0] = (bf16_t)(v[0] + b4[0]); o[1] = (bf16_t)(v[1] + b4[1]);
          o[2] = (bf16_t)(v[2] + b4[2]); o[3] = (bf16_t)(v[3] + b4[3]);
          *reinterpret_cast<bf16x4*>((bf16_t*)Cp + bz * sC + rowbase + c4) = o;
        } else {
          *reinterpret_cast<f32x4*>((float*)Cp + bz * sC + rowbase + c4) = v;
        }
      }
    }
  }
}

extern "C" void kernel_launch(void* const* d_in, const int* in_sizes, int n_in,
                              void* d_out, int out_size, void* d_ws, size_t ws_size,
                              hipStream_t stream) {
  const float* queries = (const float*)d_in[0];
  const float* values  = (const float*)d_in[1];
  const int*   mask    = (const int*)d_in[2];
  const float* Wq = (const float*)d_in[3];
  const float* bq = (const float*)d_in[4];
  const float* Wk = (const float*)d_in[5];
  const float* bk = (const float*)d_in[6];
  const float* Wv = (const float*)d_in[7];
  const float* bv = (const float*)d_in[8];

  // B=8, L=2048, D=768. Workspace layout (bytes):
  char* ws = (char*)d_ws;
  bf16_t* qb  = (bf16_t*)(ws + 0);          // queries bf16   25165824
  bf16_t* vb  = (bf16_t*)(ws + 25165824);   // values bf16    25165824
  bf16_t* wqb = (bf16_t*)(ws + 50331648);   // Wq bf16         1179648
  bf16_t* wkb = (bf16_t*)(ws + 51511296);   // Wk bf16         1179648
  bf16_t* wvb = (bf16_t*)(ws + 52690944);   // Wv bf16         1179648
  bf16_t* qp  = (bf16_t*)(ws + 53870592);   // q_proj         25165824
  bf16_t* vp  = (bf16_t*)(ws + 79036416);   // v_proj         25165824
  bf16_t* kp  = (bf16_t*)(ws + 104202240);  // k_proj         25165824
  bf16_t* vpT = (bf16_t*)(ws + 129368064);  // v_proj^T       25165824
  bf16_t* P   = (bf16_t*)(ws + 154533888);  // sigmoid scores 67108864
  unsigned long long* mbits = (unsigned long long*)(ws + 221642752);  // 4194304
  // total: 225837056

  // mask pack (ballot, coalesced): 33.55M ints / 512 per wave
  mask_pack_kernel<<<16384, 256, 0, stream>>>(mask, mbits);

  // converts: q+v in one launch, 3 weights in one launch
  conv2_kernel<<<dim3(12288, 1, 2), 256, 0, stream>>>(queries, values, qb, vb, 3145728);
  conv3_kernel<<<dim3(576, 1, 3), 256, 0, stream>>>(Wq, Wk, Wv, wqb, wkb, wvb, 147456);

  const dim3 blk2(512);

  // q-proj & v-proj batched (independent): z=0 qb*Wq+bq->qp, z=1 vb*Wv+bv->vp
  gemm8p_kernel<0><<<dim3(64, 3, 2), blk2, 0, stream>>>(
      qb, wqb, bq, nullptr, qp, 16384, 768, 768, 0, 0, 0, 0,
      vb, wvb, bv, vp);
  // k-proj (faithful quirk: k = Linear_k(v_proj))
  gemm8p_kernel<0><<<dim3(64, 3, 1), blk2, 0, stream>>>(
      vp, wkb, bk, nullptr, kp, 16384, 768, 768, 0, 0, 0, 0,
      vp, wkb, bk, kp);

  // v_proj [b][2048][768] -> v_projT [b][768][2048]
  transpose_bf16_kernel<<<dim3(32, 12, 8), 256, 0, stream>>>(vp, vpT, 2048, 768);

  // P = sigmoid(mask(q k^T)) : per batch [2048,2048], K=768; mask = packed bits
  gemm8p_kernel<1><<<dim3(8, 8, 8), blk2, 0, stream>>>(
      qp, kp, nullptr, (const unsigned*)mbits, P, 2048, 2048, 768,
      (long)2048 * 768, (long)2048 * 768, (long)2048 * 2048, (long)2048 * 64,
      nullptr, nullptr, nullptr, nullptr);

  // context = P v : per batch [2048,768], K=2048, fp32 out
  gemm8p_kernel<2><<<dim3(8, 3, 8), blk2, 0, stream>>>(
      P, vpT, nullptr, nullptr, d_out, 2048, 768, 2048,
      (long)2048 * 2048, (long)768 * 2048, (long)2048 * 768, 0,
      nullptr, nullptr, nullptr, nullptr);
}

// Round 9
// 262.654 us; speedup vs baseline: 1.9655x; 1.0347x over previous
//
#include <hip/hip_runtime.h>
#include <hip/hip_bf16.h>

typedef __bf16 bf16_t;
typedef __bf16 bf16x8 __attribute__((ext_vector_type(8)));
typedef __bf16 bf16x4 __attribute__((ext_vector_type(4)));
typedef float  f32x4  __attribute__((ext_vector_type(4)));

#define LDS_DST(p) ((__attribute__((address_space(3))) void*)(p))
#define GLB_SRC(p) ((const __attribute__((address_space(1))) void*)(p))

#define SBAR()   asm volatile("s_barrier" ::: "memory")
#define WVM8()   asm volatile("s_waitcnt vmcnt(8)" ::: "memory")
#define WVM4()   asm volatile("s_waitcnt vmcnt(4)" ::: "memory")
#define WVM0()   asm volatile("s_waitcnt vmcnt(0)" ::: "memory")
#define SP1()    __builtin_amdgcn_s_setprio(1)
#define SP0()    __builtin_amdgcn_s_setprio(0)

// ============== fused prep: mask pack + all fp32->bf16 converts ==============
// flat grid ranges: [0,16384) pack | [16384,+12288) q | [+12288) v |
//                   [+576) Wq | [+576) Wk | [+576) Wv.  Total 42688 blocks.
__global__ void __launch_bounds__(256)
prep_kernel(const int* __restrict__ mask, unsigned long long* __restrict__ bits,
            const float* __restrict__ q_in, const float* __restrict__ v_in,
            const float* __restrict__ wq_in, const float* __restrict__ wk_in,
            const float* __restrict__ wv_in,
            bf16_t* __restrict__ qb, bf16_t* __restrict__ vb,
            bf16_t* __restrict__ wqb, bf16_t* __restrict__ wkb,
            bf16_t* __restrict__ wvb) {
  const int bid = blockIdx.x;
  const int tid = threadIdx.x;
  if (bid < 16384) {
    // mask int32 -> bitmask via ballot (u64 word k covers ints [64k,64k+64))
    const long wid = (((long)bid * 256 + tid) >> 6);
    const int lane = tid & 63;
    const long base = wid * 512;
    unsigned long long b[8];
#pragma unroll
    for (int i = 0; i < 8; ++i)
      b[i] = __ballot(mask[base + i * 64 + lane] != 0);
    if (lane == 0) {
      unsigned long long* o = bits + wid * 8;
#pragma unroll
      for (int i = 0; i < 8; ++i) o[i] = b[i];
    }
    return;
  }
  const float* in; bf16_t* out; int i;
  int r = bid - 16384;
  if (r < 24576) {
    in = (r < 12288) ? q_in : v_in;
    out = (r < 12288) ? qb : vb;
    i = (r % 12288) * 256 + tid;
  } else {
    r -= 24576;
    in = (r < 576) ? wq_in : (r < 1152 ? wk_in : wv_in);
    out = (r < 576) ? wqb : (r < 1152 ? wkb : wvb);
    i = (r % 576) * 256 + tid;
    if (i >= 147456) return;
  }
  const float4 v = reinterpret_cast<const float4*>(in)[i];
  bf16x4 o;
  o[0] = (bf16_t)v.x; o[1] = (bf16_t)v.y; o[2] = (bf16_t)v.z; o[3] = (bf16_t)v.w;
  reinterpret_cast<bf16x4*>(out)[i] = o;
}

// ---------------- bf16 transpose: in [z][R][C] -> out [z][C][R] ----------------
__global__ void __launch_bounds__(256)
transpose_bf16_kernel(const bf16_t* __restrict__ in, bf16_t* __restrict__ out,
                      int R, int C) {
  __shared__ bf16_t tile[64][72];
  const long base = (long)blockIdx.z * R * C;
  const bf16_t* ib = in + base;
  bf16_t* ob = out + base;
  const int r0 = blockIdx.x * 64, c0 = blockIdx.y * 64;
  const int tid = threadIdx.x;
  const int rr = tid >> 3, cg = tid & 7;
#pragma unroll
  for (int p = 0; p < 2; ++p) {
    int row = p * 32 + rr;
    bf16x8 v = *reinterpret_cast<const bf16x8*>(ib + (long)(r0 + row) * C + c0 + cg * 8);
    *reinterpret_cast<bf16x8*>(&tile[row][cg * 8]) = v;
  }
  __syncthreads();
#pragma unroll
  for (int p = 0; p < 2; ++p) {
    int c = p * 32 + rr;
    bf16x8 v;
#pragma unroll
    for (int i = 0; i < 8; ++i) v[i] = tile[cg * 8 + i][c];
    *reinterpret_cast<bf16x8*>(ob + (long)(c0 + c) * R + r0 + cg * 8) = v;
  }
}

// ========== 256x256 GEMM, 2 merged phases per K-tile, counted vmcnt ==========
// Schedule unchanged from R7 (hazard map in R7 notes). R9: supertile-aware
// XCD swizzle so each XCD's working set fits its 4 MiB L2:
//  MODE1 (QK^T, 8x8x8):  supertile = 8bx x 2by -> qp(3MB)+kp-half(0.75MB)
//  MODE2 (PV, 8x3x8):    by-major  -> vpT(3MB) resident, P-panels stream
//  MODE0 (proj, 64x3xz): by-major  -> weights(1.1MB) resident
// REGISTER BUDGET (hard limit, learned R6): acc 128 AGPR + <=16 live frags.

__device__ __forceinline__ void read_A(const char* smem, int off, bf16x8 (&af)[8], int xk0) {
#pragma unroll
  for (int mf = 0; mf < 4; ++mf)
#pragma unroll
    for (int kk = 0; kk < 2; ++kk)
      af[mf * 2 + kk] = *reinterpret_cast<const bf16x8*>(
          smem + off + mf * 2048 + (kk ? (xk0 ^ 64) : xk0));
}

__device__ __forceinline__ void read_B(const char* smem, int off, bf16x8 (&bf_)[4], int xk0) {
#pragma unroll
  for (int nf = 0; nf < 2; ++nf)
#pragma unroll
    for (int kk = 0; kk < 2; ++kk)
      bf_[nf * 2 + kk] = *reinterpret_cast<const bf16x8*>(
          smem + off + nf * 2048 + (kk ? (xk0 ^ 64) : xk0));
}

template <int MH, int NH>
__device__ __forceinline__ void mfma_q(const bf16x8 (&af)[8], const bf16x8 (&bf_)[4],
                                       f32x4 (&acc)[8][4]) {
#pragma unroll
  for (int mf = 0; mf < 4; ++mf)
#pragma unroll
    for (int nf = 0; nf < 2; ++nf)
#pragma unroll
      for (int kk = 0; kk < 2; ++kk)
        acc[MH * 4 + mf][NH * 2 + nf] = __builtin_amdgcn_mfma_f32_16x16x32_bf16(
            af[mf * 2 + kk], bf_[nf * 2 + kk], acc[MH * 4 + mf][NH * 2 + nf], 0, 0, 0);
}

#define STAGE_A(slot, mh, kt) do {                                            \
  _Pragma("unroll") for (int j_ = 0; j_ < 2; ++j_)                            \
    __builtin_amdgcn_global_load_lds(                                         \
        GLB_SRC(pA + (long)(j_ * 128 + (mh) * 64) * K + (kt)),                \
        LDS_DST(smem + (slot) * 65536 + (arow0 + j_ * 128 + (mh) * 64) * 128),\
        16, 0, 0);                                                            \
} while (0)

#define STAGE_B(slot, nh, kt) do {                                            \
  _Pragma("unroll") for (int j_ = 0; j_ < 2; ++j_)                            \
    __builtin_amdgcn_global_load_lds(                                         \
        GLB_SRC(pB + (long)(j_ * 128 + (nh) * 32) * K + (kt)),                \
        LDS_DST(smem + (slot) * 65536 + 32768 +                               \
                (brow0 + j_ * 128 + (nh) * 32) * 128),                        \
        16, 0, 0);                                                            \
} while (0)

// MODE 0: bf16 out = acc + bias[n] (z=1 uses alt pointer set A2/B2/bias2/C2)
// MODE 1: bf16 out = maskbit ? sigmoid(acc) : 0;  MODE 2: f32 out = acc
template <int MODE>
__global__ void __launch_bounds__(512, 2)
gemm8p_kernel(const bf16_t* __restrict__ A, const bf16_t* __restrict__ B,
              const float* __restrict__ bias, const unsigned* __restrict__ maskbits,
              void* __restrict__ Cout, int M, int N, int K,
              long sA, long sB, long sC, long sMask,
              const bf16_t* __restrict__ A2, const bf16_t* __restrict__ B2,
              const float* __restrict__ bias2, void* __restrict__ C2) {
  __shared__ __align__(1024) char smem[131072];

  // ---- bijective XCD chunking (m204) on the raw dispatch id, then decode in
  // supertile order so each XCD's chunk walks an L2-sized working set.
  const int gx = gridDim.x, gy = gridDim.y;
  int f0 = blockIdx.x + gx * (blockIdx.y + gy * blockIdx.z);
  const int nwg = gx * gy * (int)gridDim.z;
  const int q8 = nwg >> 3, r8 = nwg & 7;
  const int xcd = f0 & 7, idx = f0 >> 3;
  int f1 = (xcd < r8 ? xcd * (q8 + 1) : r8 * (q8 + 1) + (xcd - r8) * q8) + idx;
  int bxi, byi, bz;
  if constexpr (MODE == 1) {
    // supertile = 8bx x 2by; f1 = bx + 8*(by&1) + 16*((by>>1) + 4*bz)
    bxi = f1 & 7;
    const int byL = (f1 >> 3) & 1;
    const int st = (f1 >> 4) & 3;
    bz = f1 >> 6;
    byi = st * 2 + byL;
  } else {
    // by-major: f1 = by + gy*(bx + gx*bz)
    byi = f1 % gy;
    const int t = f1 / gy;
    bxi = t % gx;
    bz = t / gx;
  }

  const bf16_t* Ab; const bf16_t* Bb;
  const float* biasp = bias; void* Cp = Cout;
  if constexpr (MODE == 0) {
    if (bz) { Ab = A2; Bb = B2; biasp = bias2; Cp = C2; }
    else    { Ab = A;  Bb = B; }
  } else {
    Ab = A + bz * sA; Bb = B + bz * sB;
  }
  const int bm = bxi * 256, bn = byi * 256;
  const int tid = threadIdx.x;
  const int wave = tid >> 6, lane = tid & 63;
  const int wr = wave >> 2, wc = wave & 3;
  const int l15 = lane & 15, lg = lane >> 4;
  const int xk0 = (lg * 16) ^ ((lane & 7) << 4);
  const int NT = K >> 6;

  // staging bases
  const int lr = lane >> 3;
  const int cgs = ((lane & 7) ^ lr) * 8;
  const int arow0 = wave * 8;
  const int brow0 = (wave >> 2) * 64 + (wave & 3) * 8;
  const bf16_t* pA = Ab + (long)(bm + arow0 + lr) * K + cgs;
  const bf16_t* pB = Bb + (long)(bn + brow0 + lr) * K + cgs;

  // ds_read base offsets
  const int aoff = wr * 16384 + l15 * 128;          // + slot*65536 + mh*8192
  const int boff = 32768 + wc * 8192 + l15 * 128;   // + slot*65536 + nh*4096

  f32x4 acc[8][4] = {};
  bf16x8 afX[8], bfB[4], bf0[4];

  // ---- prologue: t0 full (8 instrs), then A0/B0(1) (4), B1/A1(1) (4) ----
  STAGE_A(0, 0, 0); STAGE_B(0, 0, 0); STAGE_B(0, 1, 0); STAGE_A(0, 1, 0);
  STAGE_A(1, 0, 64); STAGE_B(1, 0, 64);
  STAGE_B(1, 1, 64); STAGE_A(1, 1, 64);
  WVM8();   // tile0's 8 instrs landed
  SBAR();
  read_A(smem, aoff + 0, afX, xk0);   // A0(t0)
  read_B(smem, boff + 0, bf0, xk0);   // B0(t0)

  int slot = 0;
  for (int t = 0; t + 2 < NT; ++t) {
    const int so = slot * 65536, sn = (slot ^ 1) * 65536;
    const int k2 = (t + 2) << 6;
    // ---- P_a ----
    read_B(smem, so + boff + 4096, bfB, xk0);        // B1(t)
    STAGE_A(slot, 0, k2); STAGE_B(slot, 0, k2);      // A0(t+2), B0(t+2)
    SP1(); mfma_q<0, 0>(afX, bf0, acc); SP0();
    SP1(); mfma_q<0, 1>(afX, bfB, acc); SP0();
    read_A(smem, so + aoff + 8192, afX, xk0);        // A1(t)
    WVM8(); SBAR();                                  // c1
    // ---- P_b ----
    SP1(); mfma_q<1, 1>(afX, bfB, acc); SP0();
    SP1(); mfma_q<1, 0>(afX, bf0, acc); SP0();
    read_A(smem, sn + aoff + 0, afX, xk0);           // A0(t+1)
    read_B(smem, sn + boff + 0, bf0, xk0);           // B0(t+1)
    STAGE_B(slot, 1, k2); STAGE_A(slot, 1, k2);      // B1(t+2), A1(t+2)
    WVM8(); SBAR();                                  // c2
    slot ^= 1;
  }

  // ---- drain: tiles NT-2 (so), NT-1 (sn); no staging ----
  {
    const int so = slot * 65536, sn = (slot ^ 1) * 65536;
    read_B(smem, so + boff + 4096, bfB, xk0);        // B1(NT-2)
    SP1(); mfma_q<0, 0>(afX, bf0, acc); SP0();
    SP1(); mfma_q<0, 1>(afX, bfB, acc); SP0();
    read_A(smem, so + aoff + 8192, afX, xk0);        // A1(NT-2)
    WVM4(); SBAR();
    SP1(); mfma_q<1, 1>(afX, bfB, acc); SP0();
    SP1(); mfma_q<1, 0>(afX, bf0, acc); SP0();
    read_A(smem, sn + aoff + 0, afX, xk0);           // A0(NT-1)
    read_B(smem, sn + boff + 0, bf0, xk0);           // B0(NT-1)
    WVM0(); SBAR();
    // last tile
    read_B(smem, sn + boff + 4096, bfB, xk0);        // B1(NT-1)
    SP1(); mfma_q<0, 0>(afX, bf0, acc); SP0();
    SP1(); mfma_q<0, 1>(afX, bfB, acc); SP0();
    read_A(smem, sn + aoff + 8192, afX, xk0);        // A1(NT-1)
    SP1(); mfma_q<1, 1>(afX, bfB, acc); SP0();
    SP1(); mfma_q<1, 0>(afX, bf0, acc); SP0();
  }

  // ---- C-write: 4 rounds of 64-row LDS rearrange, coalesced I/O ----
  // (fully unrolled: acc indices must stay compile-time -- rule #20)
  float* eb = (float*)smem;
  const int lrow = tid >> 3, t7 = tid & 7;
#pragma unroll
  for (int rd = 0; rd < 4; ++rd) {
    __syncthreads();
#pragma unroll
    for (int fi = 0; fi < 2; ++fi)
#pragma unroll
      for (int nf = 0; nf < 4; ++nf)
#pragma unroll
        for (int r = 0; r < 4; ++r) {
          const int lr2 = wr * 32 + fi * 16 + lg * 4 + r;
          eb[lr2 * 256 + wc * 64 + nf * 16 + l15] = acc[rd * 2 + fi][nf][r];
        }
    __syncthreads();
    const int growt = rd * 32 + lrow + ((lrow >> 5) * 96);
    const long rowbase = (long)(bm + growt) * N + bn;
    if constexpr (MODE == 1) {
      const unsigned* mw =
          maskbits + bz * sMask + (long)(bm + growt) * (N >> 5) + (bn >> 5);
      const uint4 w0 = *reinterpret_cast<const uint4*>(mw);
      const uint4 w1 = *reinterpret_cast<const uint4*>(mw + 4);
      const unsigned wq[8] = {w0.x, w0.y, w0.z, w0.w, w1.x, w1.y, w1.z, w1.w};
#pragma unroll
      for (int q = 0; q < 8; ++q) {
        const int c4 = (q * 8 + t7) * 4;
        const f32x4 v = *reinterpret_cast<const f32x4*>(&eb[lrow * 256 + c4]);
        const unsigned nib = (wq[q] >> (t7 * 4)) & 0xFu;
        bf16x4 o;
        o[0] = (bf16_t)((nib & 1u) ? __builtin_amdgcn_rcpf(1.f + __expf(-v[0])) : 0.f);
        o[1] = (bf16_t)((nib & 2u) ? __builtin_amdgcn_rcpf(1.f + __expf(-v[1])) : 0.f);
        o[2] = (bf16_t)((nib & 4u) ? __builtin_amdgcn_rcpf(1.f + __expf(-v[2])) : 0.f);
        o[3] = (bf16_t)((nib & 8u) ? __builtin_amdgcn_rcpf(1.f + __expf(-v[3])) : 0.f);
        *reinterpret_cast<bf16x4*>((bf16_t*)Cp + bz * sC + rowbase + c4) = o;
      }
    } else {
#pragma unroll
      for (int q = 0; q < 8; ++q) {
        const int c4 = (q * 8 + t7) * 4;
        const f32x4 v = *reinterpret_cast<const f32x4*>(&eb[lrow * 256 + c4]);
        if constexpr (MODE == 0) {
          const f32x4 b4 = *reinterpret_cast<const f32x4*>(biasp + bn + c4);
          bf16x4 o;
          o[0] = (bf16_t)(v[0] + b4[0]); o[1] = (bf16_t)(v[1] + b4[1]);
          o[2] = (bf16_t)(v[2] + b4[2]); o[3] = (bf16_t)(v[3] + b4[3]);
          *reinterpret_cast<bf16x4*>((bf16_t*)Cp + bz * sC + rowbase + c4) = o;
        } else {
          *reinterpret_cast<f32x4*>((float*)Cp + bz * sC + rowbase + c4) = v;
        }
      }
    }
  }
}

extern "C" void kernel_launch(void* const* d_in, const int* in_sizes, int n_in,
                              void* d_out, int out_size, void* d_ws, size_t ws_size,
                              hipStream_t stream) {
  const float* queries = (const float*)d_in[0];
  const float* values  = (const float*)d_in[1];
  const int*   mask    = (const int*)d_in[2];
  const float* Wq = (const float*)d_in[3];
  const float* bq = (const float*)d_in[4];
  const float* Wk = (const float*)d_in[5];
  const float* bk = (const float*)d_in[6];
  const float* Wv = (const float*)d_in[7];
  const float* bv = (const float*)d_in[8];

  // B=8, L=2048, D=768. Workspace layout (bytes):
  char* ws = (char*)d_ws;
  bf16_t* qb  = (bf16_t*)(ws + 0);          // queries bf16   25165824
  bf16_t* vb  = (bf16_t*)(ws + 25165824);   // values bf16    25165824
  bf16_t* wqb = (bf16_t*)(ws + 50331648);   // Wq bf16         1179648
  bf16_t* wkb = (bf16_t*)(ws + 51511296);   // Wk bf16         1179648
  bf16_t* wvb = (bf16_t*)(ws + 52690944);   // Wv bf16         1179648
  bf16_t* qp  = (bf16_t*)(ws + 53870592);   // q_proj         25165824
  bf16_t* vp  = (bf16_t*)(ws + 79036416);   // v_proj         25165824
  bf16_t* kp  = (bf16_t*)(ws + 104202240);  // k_proj         25165824
  bf16_t* vpT = (bf16_t*)(ws + 129368064);  // v_proj^T       25165824
  bf16_t* P   = (bf16_t*)(ws + 154533888);  // sigmoid scores 67108864
  unsigned long long* mbits = (unsigned long long*)(ws + 221642752);  // 4194304
  // total: 225837056

  // fused prep: pack + q/v converts + 3 weight converts (one launch)
  prep_kernel<<<42688, 256, 0, stream>>>(mask, mbits, queries, values,
                                         Wq, Wk, Wv, qb, vb, wqb, wkb, wvb);

  const dim3 blk2(512);

  // q-proj & v-proj batched (independent): z=0 qb*Wq+bq->qp, z=1 vb*Wv+bv->vp
  gemm8p_kernel<0><<<dim3(64, 3, 2), blk2, 0, stream>>>(
      qb, wqb, bq, nullptr, qp, 16384, 768, 768, 0, 0, 0, 0,
      vb, wvb, bv, vp);
  // k-proj (faithful quirk: k = Linear_k(v_proj))
  gemm8p_kernel<0><<<dim3(64, 3, 1), blk2, 0, stream>>>(
      vp, wkb, bk, nullptr, kp, 16384, 768, 768, 0, 0, 0, 0,
      vp, wkb, bk, kp);

  // v_proj [b][2048][768] -> v_projT [b][768][2048]
  transpose_bf16_kernel<<<dim3(32, 12, 8), 256, 0, stream>>>(vp, vpT, 2048, 768);

  // P = sigmoid(mask(q k^T)) : per batch [2048,2048], K=768; mask = packed bits
  gemm8p_kernel<1><<<dim3(8, 8, 8), blk2, 0, stream>>>(
      qp, kp, nullptr, (const unsigned*)mbits, P, 2048, 2048, 768,
      (long)2048 * 768, (long)2048 * 768, (long)2048 * 2048, (long)2048 * 64,
      nullptr, nullptr, nullptr, nullptr);

  // context = P v : per batch [2048,768], K=2048, fp32 out
  gemm8p_kernel<2><<<dim3(8, 3, 8), blk2, 0, stream>>>(
      P, vpT, nullptr, nullptr, d_out, 2048, 768, 2048,
      (long)2048 * 2048, (long)768 * 2048, (long)2048 * 768, 0,
      nullptr, nullptr, nullptr, nullptr);
}

// Round 10
// 259.299 us; speedup vs baseline: 1.9909x; 1.0129x over previous
//
#include <hip/hip_runtime.h>
#include <hip/hip_bf16.h>

typedef __bf16 bf16_t;
typedef __bf16 bf16x8 __attribute__((ext_vector_type(8)));
typedef __bf16 bf16x4 __attribute__((ext_vector_type(4)));
typedef float  f32x4  __attribute__((ext_vector_type(4)));

#define LDS_DST(p) ((__attribute__((address_space(3))) void*)(p))
#define GLB_SRC(p) ((const __attribute__((address_space(1))) void*)(p))

#define SBAR()   asm volatile("s_barrier" ::: "memory")
#define WVM8()   asm volatile("s_waitcnt vmcnt(8)" ::: "memory")
#define WVM4()   asm volatile("s_waitcnt vmcnt(4)" ::: "memory")
#define WVM0()   asm volatile("s_waitcnt vmcnt(0)" ::: "memory")
#define SP1()    __builtin_amdgcn_s_setprio(1)
#define SP0()    __builtin_amdgcn_s_setprio(0)

// ============== fp32 -> bf16 converts, one launch ==============
// flat ranges: [0,12288) q | [+12288) v | [+576) Wq | [+576) Wk | [+576) Wv
__global__ void __launch_bounds__(256)
convert_kernel(const float* __restrict__ q_in, const float* __restrict__ v_in,
               const float* __restrict__ wq_in, const float* __restrict__ wk_in,
               const float* __restrict__ wv_in,
               bf16_t* __restrict__ qb, bf16_t* __restrict__ vb,
               bf16_t* __restrict__ wqb, bf16_t* __restrict__ wkb,
               bf16_t* __restrict__ wvb) {
  const int tid = threadIdx.x;
  int r = blockIdx.x;
  const float* in; bf16_t* out; int i;
  if (r < 24576) {
    in = (r < 12288) ? q_in : v_in;
    out = (r < 12288) ? qb : vb;
    i = (r % 12288) * 256 + tid;
  } else {
    r -= 24576;
    in = (r < 576) ? wq_in : (r < 1152 ? wk_in : wv_in);
    out = (r < 576) ? wqb : (r < 1152 ? wkb : wvb);
    i = (r % 576) * 256 + tid;
  }
  const float4 v = reinterpret_cast<const float4*>(in)[i];
  bf16x4 o;
  o[0] = (bf16_t)v.x; o[1] = (bf16_t)v.y; o[2] = (bf16_t)v.z; o[3] = (bf16_t)v.w;
  reinterpret_cast<bf16x4*>(out)[i] = o;
}

// ---------------- bf16 transpose: in [z][R][C] -> out [z][C][R] ----------------
__global__ void __launch_bounds__(256)
transpose_bf16_kernel(const bf16_t* __restrict__ in, bf16_t* __restrict__ out,
                      int R, int C) {
  __shared__ bf16_t tile[64][72];
  const long base = (long)blockIdx.z * R * C;
  const bf16_t* ib = in + base;
  bf16_t* ob = out + base;
  const int r0 = blockIdx.x * 64, c0 = blockIdx.y * 64;
  const int tid = threadIdx.x;
  const int rr = tid >> 3, cg = tid & 7;
#pragma unroll
  for (int p = 0; p < 2; ++p) {
    int row = p * 32 + rr;
    bf16x8 v = *reinterpret_cast<const bf16x8*>(ib + (long)(r0 + row) * C + c0 + cg * 8);
    *reinterpret_cast<bf16x8*>(&tile[row][cg * 8]) = v;
  }
  __syncthreads();
#pragma unroll
  for (int p = 0; p < 2; ++p) {
    int c = p * 32 + rr;
    bf16x8 v;
#pragma unroll
    for (int i = 0; i < 8; ++i) v[i] = tile[cg * 8 + i][c];
    *reinterpret_cast<bf16x8*>(ob + (long)(c0 + c) * R + r0 + cg * 8) = v;
  }
}

// ========== 256x256 GEMM, 2 merged phases per K-tile, counted vmcnt ==========
// Schedule unchanged from R7 (hazard map in R7 notes). R9 supertile swizzle
// kept. R10: MODE1 reads the int32 mask DIRECTLY in the epilogue (8x int4
// coalesced loads per round, issued before the round's first barrier so the
// LDS rearrange hides the latency) -- the standalone pack kernel measured
// 60+ us at 2 TB/s and is removed.
// REGISTER BUDGET (hard limit, learned R6): acc 128 AGPR + <=16 live frags
// in main loop; epilogue may use freed frag regs (mask int4 x8 = 32 VGPR ok).

__device__ __forceinline__ void read_A(const char* smem, int off, bf16x8 (&af)[8], int xk0) {
#pragma unroll
  for (int mf = 0; mf < 4; ++mf)
#pragma unroll
    for (int kk = 0; kk < 2; ++kk)
      af[mf * 2 + kk] = *reinterpret_cast<const bf16x8*>(
          smem + off + mf * 2048 + (kk ? (xk0 ^ 64) : xk0));
}

__device__ __forceinline__ void read_B(const char* smem, int off, bf16x8 (&bf_)[4], int xk0) {
#pragma unroll
  for (int nf = 0; nf < 2; ++nf)
#pragma unroll
    for (int kk = 0; kk < 2; ++kk)
      bf_[nf * 2 + kk] = *reinterpret_cast<const bf16x8*>(
          smem + off + nf * 2048 + (kk ? (xk0 ^ 64) : xk0));
}

template <int MH, int NH>
__device__ __forceinline__ void mfma_q(const bf16x8 (&af)[8], const bf16x8 (&bf_)[4],
                                       f32x4 (&acc)[8][4]) {
#pragma unroll
  for (int mf = 0; mf < 4; ++mf)
#pragma unroll
    for (int nf = 0; nf < 2; ++nf)
#pragma unroll
      for (int kk = 0; kk < 2; ++kk)
        acc[MH * 4 + mf][NH * 2 + nf] = __builtin_amdgcn_mfma_f32_16x16x32_bf16(
            af[mf * 2 + kk], bf_[nf * 2 + kk], acc[MH * 4 + mf][NH * 2 + nf], 0, 0, 0);
}

#define STAGE_A(slot, mh, kt) do {                                            \
  _Pragma("unroll") for (int j_ = 0; j_ < 2; ++j_)                            \
    __builtin_amdgcn_global_load_lds(                                         \
        GLB_SRC(pA + (long)(j_ * 128 + (mh) * 64) * K + (kt)),                \
        LDS_DST(smem + (slot) * 65536 + (arow0 + j_ * 128 + (mh) * 64) * 128),\
        16, 0, 0);                                                            \
} while (0)

#define STAGE_B(slot, nh, kt) do {                                            \
  _Pragma("unroll") for (int j_ = 0; j_ < 2; ++j_)                            \
    __builtin_amdgcn_global_load_lds(                                         \
        GLB_SRC(pB + (long)(j_ * 128 + (nh) * 32) * K + (kt)),                \
        LDS_DST(smem + (slot) * 65536 + 32768 +                               \
                (brow0 + j_ * 128 + (nh) * 32) * 128),                        \
        16, 0, 0);                                                            \
} while (0)

// MODE 0: bf16 out = acc + bias[n] (z=1 uses alt pointer set A2/B2/bias2/C2)
// MODE 1: bf16 out = mask ? sigmoid(acc) : 0 (mask read int32, direct)
// MODE 2: f32 out = acc
template <int MODE>
__global__ void __launch_bounds__(512, 2)
gemm8p_kernel(const bf16_t* __restrict__ A, const bf16_t* __restrict__ B,
              const float* __restrict__ bias, const int* __restrict__ mask,
              void* __restrict__ Cout, int M, int N, int K,
              long sA, long sB, long sC, long sMask,
              const bf16_t* __restrict__ A2, const bf16_t* __restrict__ B2,
              const float* __restrict__ bias2, void* __restrict__ C2) {
  __shared__ __align__(1024) char smem[131072];

  // ---- bijective XCD chunking (m204) + supertile decode (R9) ----
  const int gx = gridDim.x, gy = gridDim.y;
  int f0 = blockIdx.x + gx * (blockIdx.y + gy * blockIdx.z);
  const int nwg = gx * gy * (int)gridDim.z;
  const int q8 = nwg >> 3, r8 = nwg & 7;
  const int xcd = f0 & 7, idx = f0 >> 3;
  int f1 = (xcd < r8 ? xcd * (q8 + 1) : r8 * (q8 + 1) + (xcd - r8) * q8) + idx;
  int bxi, byi, bz;
  if constexpr (MODE == 1) {
    // supertile = 8bx x 2by; f1 = bx + 8*(by&1) + 16*((by>>1) + 4*bz)
    bxi = f1 & 7;
    const int byL = (f1 >> 3) & 1;
    const int st = (f1 >> 4) & 3;
    bz = f1 >> 6;
    byi = st * 2 + byL;
  } else {
    // by-major: f1 = by + gy*(bx + gx*bz)
    byi = f1 % gy;
    const int t = f1 / gy;
    bxi = t % gx;
    bz = t / gx;
  }

  const bf16_t* Ab; const bf16_t* Bb;
  const float* biasp = bias; void* Cp = Cout;
  if constexpr (MODE == 0) {
    if (bz) { Ab = A2; Bb = B2; biasp = bias2; Cp = C2; }
    else    { Ab = A;  Bb = B; }
  } else {
    Ab = A + bz * sA; Bb = B + bz * sB;
  }
  const int bm = bxi * 256, bn = byi * 256;
  const int tid = threadIdx.x;
  const int wave = tid >> 6, lane = tid & 63;
  const int wr = wave >> 2, wc = wave & 3;
  const int l15 = lane & 15, lg = lane >> 4;
  const int xk0 = (lg * 16) ^ ((lane & 7) << 4);
  const int NT = K >> 6;

  // staging bases
  const int lr = lane >> 3;
  const int cgs = ((lane & 7) ^ lr) * 8;
  const int arow0 = wave * 8;
  const int brow0 = (wave >> 2) * 64 + (wave & 3) * 8;
  const bf16_t* pA = Ab + (long)(bm + arow0 + lr) * K + cgs;
  const bf16_t* pB = Bb + (long)(bn + brow0 + lr) * K + cgs;

  // ds_read base offsets
  const int aoff = wr * 16384 + l15 * 128;          // + slot*65536 + mh*8192
  const int boff = 32768 + wc * 8192 + l15 * 128;   // + slot*65536 + nh*4096

  f32x4 acc[8][4] = {};
  bf16x8 afX[8], bfB[4], bf0[4];

  // ---- prologue: t0 full (8 instrs), then A0/B0(1) (4), B1/A1(1) (4) ----
  STAGE_A(0, 0, 0); STAGE_B(0, 0, 0); STAGE_B(0, 1, 0); STAGE_A(0, 1, 0);
  STAGE_A(1, 0, 64); STAGE_B(1, 0, 64);
  STAGE_B(1, 1, 64); STAGE_A(1, 1, 64);
  WVM8();   // tile0's 8 instrs landed
  SBAR();
  read_A(smem, aoff + 0, afX, xk0);   // A0(t0)
  read_B(smem, boff + 0, bf0, xk0);   // B0(t0)

  int slot = 0;
  for (int t = 0; t + 2 < NT; ++t) {
    const int so = slot * 65536, sn = (slot ^ 1) * 65536;
    const int k2 = (t + 2) << 6;
    // ---- P_a ----
    read_B(smem, so + boff + 4096, bfB, xk0);        // B1(t)
    STAGE_A(slot, 0, k2); STAGE_B(slot, 0, k2);      // A0(t+2), B0(t+2)
    SP1(); mfma_q<0, 0>(afX, bf0, acc); SP0();
    SP1(); mfma_q<0, 1>(afX, bfB, acc); SP0();
    read_A(smem, so + aoff + 8192, afX, xk0);        // A1(t)
    WVM8(); SBAR();                                  // c1
    // ---- P_b ----
    SP1(); mfma_q<1, 1>(afX, bfB, acc); SP0();
    SP1(); mfma_q<1, 0>(afX, bf0, acc); SP0();
    read_A(smem, sn + aoff + 0, afX, xk0);           // A0(t+1)
    read_B(smem, sn + boff + 0, bf0, xk0);           // B0(t+1)
    STAGE_B(slot, 1, k2); STAGE_A(slot, 1, k2);      // B1(t+2), A1(t+2)
    WVM8(); SBAR();                                  // c2
    slot ^= 1;
  }

  // ---- drain: tiles NT-2 (so), NT-1 (sn); no staging ----
  {
    const int so = slot * 65536, sn = (slot ^ 1) * 65536;
    read_B(smem, so + boff + 4096, bfB, xk0);        // B1(NT-2)
    SP1(); mfma_q<0, 0>(afX, bf0, acc); SP0();
    SP1(); mfma_q<0, 1>(afX, bfB, acc); SP0();
    read_A(smem, so + aoff + 8192, afX, xk0);        // A1(NT-2)
    WVM4(); SBAR();
    SP1(); mfma_q<1, 1>(afX, bfB, acc); SP0();
    SP1(); mfma_q<1, 0>(afX, bf0, acc); SP0();
    read_A(smem, sn + aoff + 0, afX, xk0);           // A0(NT-1)
    read_B(smem, sn + boff + 0, bf0, xk0);           // B0(NT-1)
    WVM0(); SBAR();
    // last tile
    read_B(smem, sn + boff + 4096, bfB, xk0);        // B1(NT-1)
    SP1(); mfma_q<0, 0>(afX, bf0, acc); SP0();
    SP1(); mfma_q<0, 1>(afX, bfB, acc); SP0();
    read_A(smem, sn + aoff + 8192, afX, xk0);        // A1(NT-1)
    SP1(); mfma_q<1, 1>(afX, bfB, acc); SP0();
    SP1(); mfma_q<1, 0>(afX, bf0, acc); SP0();
  }

  // ---- C-write: 4 rounds of 64-row LDS rearrange, coalesced I/O ----
  // (fully unrolled: acc indices must stay compile-time -- rule #20)
  // MODE1: per-round mask int4 loads issued BEFORE the round's first barrier;
  // the 2 barriers + LDS rearrange hide their latency (T14).
  float* eb = (float*)smem;
  const int lrow = tid >> 3, t7 = tid & 7;
#pragma unroll
  for (int rd = 0; rd < 4; ++rd) {
    const int growt = rd * 32 + lrow + ((lrow >> 5) * 96);
    const long rowbase = (long)(bm + growt) * N + bn;
    int4 m4[8];
    if constexpr (MODE == 1) {
      const int* mrow = mask + bz * sMask + rowbase;
#pragma unroll
      for (int q = 0; q < 8; ++q)
        m4[q] = *reinterpret_cast<const int4*>(mrow + (q * 8 + t7) * 4);
    }
    __syncthreads();
#pragma unroll
    for (int fi = 0; fi < 2; ++fi)
#pragma unroll
      for (int nf = 0; nf < 4; ++nf)
#pragma unroll
        for (int r = 0; r < 4; ++r) {
          const int lr2 = wr * 32 + fi * 16 + lg * 4 + r;
          eb[lr2 * 256 + wc * 64 + nf * 16 + l15] = acc[rd * 2 + fi][nf][r];
        }
    __syncthreads();
#pragma unroll
    for (int q = 0; q < 8; ++q) {
      const int c4 = (q * 8 + t7) * 4;
      const f32x4 v = *reinterpret_cast<const f32x4*>(&eb[lrow * 256 + c4]);
      if constexpr (MODE == 1) {
        bf16x4 o;
        o[0] = (bf16_t)(m4[q].x ? __builtin_amdgcn_rcpf(1.f + __expf(-v[0])) : 0.f);
        o[1] = (bf16_t)(m4[q].y ? __builtin_amdgcn_rcpf(1.f + __expf(-v[1])) : 0.f);
        o[2] = (bf16_t)(m4[q].z ? __builtin_amdgcn_rcpf(1.f + __expf(-v[2])) : 0.f);
        o[3] = (bf16_t)(m4[q].w ? __builtin_amdgcn_rcpf(1.f + __expf(-v[3])) : 0.f);
        *reinterpret_cast<bf16x4*>((bf16_t*)Cp + bz * sC + rowbase + c4) = o;
      } else if constexpr (MODE == 0) {
        const f32x4 b4 = *reinterpret_cast<const f32x4*>(biasp + bn + c4);
        bf16x4 o;
        o[0] = (bf16_t)(v[0] + b4[0]); o[1] = (bf16_t)(v[1] + b4[1]);
        o[2] = (bf16_t)(v[2] + b4[2]); o[3] = (bf16_t)(v[3] + b4[3]);
        *reinterpret_cast<bf16x4*>((bf16_t*)Cp + bz * sC + rowbase + c4) = o;
      } else {
        *reinterpret_cast<f32x4*>((float*)Cp + bz * sC + rowbase + c4) = v;
      }
    }
  }
}

extern "C" void kernel_launch(void* const* d_in, const int* in_sizes, int n_in,
                              void* d_out, int out_size, void* d_ws, size_t ws_size,
                              hipStream_t stream) {
  const float* queries = (const float*)d_in[0];
  const float* values  = (const float*)d_in[1];
  const int*   mask    = (const int*)d_in[2];
  const float* Wq = (const float*)d_in[3];
  const float* bq = (const float*)d_in[4];
  const float* Wk = (const float*)d_in[5];
  const float* bk = (const float*)d_in[6];
  const float* Wv = (const float*)d_in[7];
  const float* bv = (const float*)d_in[8];

  // B=8, L=2048, D=768. Workspace layout (bytes):
  char* ws = (char*)d_ws;
  bf16_t* qb  = (bf16_t*)(ws + 0);          // queries bf16   25165824
  bf16_t* vb  = (bf16_t*)(ws + 25165824);   // values bf16    25165824
  bf16_t* wqb = (bf16_t*)(ws + 50331648);   // Wq bf16         1179648
  bf16_t* wkb = (bf16_t*)(ws + 51511296);   // Wk bf16         1179648
  bf16_t* wvb = (bf16_t*)(ws + 52690944);   // Wv bf16         1179648
  bf16_t* qp  = (bf16_t*)(ws + 53870592);   // q_proj         25165824
  bf16_t* vp  = (bf16_t*)(ws + 79036416);   // v_proj         25165824
  bf16_t* kp  = (bf16_t*)(ws + 104202240);  // k_proj         25165824
  bf16_t* vpT = (bf16_t*)(ws + 129368064);  // v_proj^T       25165824
  bf16_t* P   = (bf16_t*)(ws + 154533888);  // sigmoid scores 67108864
  // total: 221642752

  // converts (q, v, 3 weights) in one launch
  convert_kernel<<<26304, 256, 0, stream>>>(queries, values, Wq, Wk, Wv,
                                            qb, vb, wqb, wkb, wvb);

  const dim3 blk2(512);

  // q-proj & v-proj batched (independent): z=0 qb*Wq+bq->qp, z=1 vb*Wv+bv->vp
  gemm8p_kernel<0><<<dim3(64, 3, 2), blk2, 0, stream>>>(
      qb, wqb, bq, nullptr, qp, 16384, 768, 768, 0, 0, 0, 0,
      vb, wvb, bv, vp);
  // k-proj (faithful quirk: k = Linear_k(v_proj))
  gemm8p_kernel<0><<<dim3(64, 3, 1), blk2, 0, stream>>>(
      vp, wkb, bk, nullptr, kp, 16384, 768, 768, 0, 0, 0, 0,
      vp, wkb, bk, kp);

  // v_proj [b][2048][768] -> v_projT [b][768][2048]
  transpose_bf16_kernel<<<dim3(32, 12, 8), 256, 0, stream>>>(vp, vpT, 2048, 768);

  // P = sigmoid(mask(q k^T)) : per batch [2048,2048], K=768; int32 mask direct
  gemm8p_kernel<1><<<dim3(8, 8, 8), blk2, 0, stream>>>(
      qp, kp, nullptr, mask, P, 2048, 2048, 768,
      (long)2048 * 768, (long)2048 * 768, (long)2048 * 2048, (long)2048 * 2048,
      nullptr, nullptr, nullptr, nullptr);

  // context = P v : per batch [2048,768], K=2048, fp32 out
  gemm8p_kernel<2><<<dim3(8, 3, 8), blk2, 0, stream>>>(
      P, vpT, nullptr, nullptr, d_out, 2048, 768, 2048,
      (long)2048 * 2048, (long)768 * 2048, (long)2048 * 768, 0,
      nullptr, nullptr, nullptr, nullptr);
}

// Round 11
// 253.569 us; speedup vs baseline: 2.0359x; 1.0226x over previous
//
#include <hip/hip_runtime.h>
#include <hip/hip_bf16.h>

typedef __bf16 bf16_t;
typedef __bf16 bf16x8 __attribute__((ext_vector_type(8)));
typedef __bf16 bf16x4 __attribute__((ext_vector_type(4)));
typedef float  f32x4  __attribute__((ext_vector_type(4)));

#define LDS_DST(p) ((__attribute__((address_space(3))) void*)(p))
#define GLB_SRC(p) ((const __attribute__((address_space(1))) void*)(p))

#define SBAR()   asm volatile("s_barrier" ::: "memory")
#define WVM8()   asm volatile("s_waitcnt vmcnt(8)" ::: "memory")
#define WVM4()   asm volatile("s_waitcnt vmcnt(4)" ::: "memory")
#define WVM0()   asm volatile("s_waitcnt vmcnt(0)" ::: "memory")
#define SP1()    __builtin_amdgcn_s_setprio(1)
#define SP0()    __builtin_amdgcn_s_setprio(0)

// ============== fp32 -> bf16 converts, one launch, 4x float4/thread ==========
// flat ranges: [0,3072) q | [+3072) v | [+144) Wq | [+144) Wk | [+144) Wv
__global__ void __launch_bounds__(256)
convert_kernel(const float* __restrict__ q_in, const float* __restrict__ v_in,
               const float* __restrict__ wq_in, const float* __restrict__ wk_in,
               const float* __restrict__ wv_in,
               bf16_t* __restrict__ qb, bf16_t* __restrict__ vb,
               bf16_t* __restrict__ wqb, bf16_t* __restrict__ wkb,
               bf16_t* __restrict__ wvb) {
  const int tid = threadIdx.x;
  int r = blockIdx.x;
  const float* in; bf16_t* out; int base;
  if (r < 6144) {
    in = (r < 3072) ? q_in : v_in;
    out = (r < 3072) ? qb : vb;
    base = (r % 3072) * 1024;
  } else {
    r -= 6144;
    in = (r < 144) ? wq_in : (r < 288 ? wk_in : wv_in);
    out = (r < 144) ? wqb : (r < 288 ? wkb : wvb);
    base = (r % 144) * 1024;
  }
#pragma unroll
  for (int j = 0; j < 4; ++j) {
    const int i = base + j * 256 + tid;
    const float4 v = reinterpret_cast<const float4*>(in)[i];
    bf16x4 o;
    o[0] = (bf16_t)v.x; o[1] = (bf16_t)v.y; o[2] = (bf16_t)v.z; o[3] = (bf16_t)v.w;
    reinterpret_cast<bf16x4*>(out)[i] = o;
  }
}

// ---------------- bf16 transpose: in [z][R][C] -> out [z][C][R] ----------------
__global__ void __launch_bounds__(256)
transpose_bf16_kernel(const bf16_t* __restrict__ in, bf16_t* __restrict__ out,
                      int R, int C) {
  __shared__ bf16_t tile[64][72];
  const long base = (long)blockIdx.z * R * C;
  const bf16_t* ib = in + base;
  bf16_t* ob = out + base;
  const int r0 = blockIdx.x * 64, c0 = blockIdx.y * 64;
  const int tid = threadIdx.x;
  const int rr = tid >> 3, cg = tid & 7;
#pragma unroll
  for (int p = 0; p < 2; ++p) {
    int row = p * 32 + rr;
    bf16x8 v = *reinterpret_cast<const bf16x8*>(ib + (long)(r0 + row) * C + c0 + cg * 8);
    *reinterpret_cast<bf16x8*>(&tile[row][cg * 8]) = v;
  }
  __syncthreads();
#pragma unroll
  for (int p = 0; p < 2; ++p) {
    int c = p * 32 + rr;
    bf16x8 v;
#pragma unroll
    for (int i = 0; i < 8; ++i) v[i] = tile[cg * 8 + i][c];
    *reinterpret_cast<bf16x8*>(ob + (long)(c0 + c) * R + r0 + cg * 8) = v;
  }
}

// ========== 256x256 GEMM, 2 merged phases per K-tile, counted vmcnt ==========
// Main loop unchanged from R7 (hazard map in R7 notes); R9 supertile swizzle.
// R11: epilogue double-buffered (2x64KB eb chunks, 1 barrier/round instead of
// 2) + MODE1 mask double-prefetch (m4a/m4b, issued a full round early - T14).
// REGISTER BUDGET (hard limit, learned R6): acc 128 AGPR + <=16 live frags in
// main loop; epilogue reuses freed frag regs (2x32 VGPR mask buffers ok).

__device__ __forceinline__ void read_A(const char* smem, int off, bf16x8 (&af)[8], int xk0) {
#pragma unroll
  for (int mf = 0; mf < 4; ++mf)
#pragma unroll
    for (int kk = 0; kk < 2; ++kk)
      af[mf * 2 + kk] = *reinterpret_cast<const bf16x8*>(
          smem + off + mf * 2048 + (kk ? (xk0 ^ 64) : xk0));
}

__device__ __forceinline__ void read_B(const char* smem, int off, bf16x8 (&bf_)[4], int xk0) {
#pragma unroll
  for (int nf = 0; nf < 2; ++nf)
#pragma unroll
    for (int kk = 0; kk < 2; ++kk)
      bf_[nf * 2 + kk] = *reinterpret_cast<const bf16x8*>(
          smem + off + nf * 2048 + (kk ? (xk0 ^ 64) : xk0));
}

template <int MH, int NH>
__device__ __forceinline__ void mfma_q(const bf16x8 (&af)[8], const bf16x8 (&bf_)[4],
                                       f32x4 (&acc)[8][4]) {
#pragma unroll
  for (int mf = 0; mf < 4; ++mf)
#pragma unroll
    for (int nf = 0; nf < 2; ++nf)
#pragma unroll
      for (int kk = 0; kk < 2; ++kk)
        acc[MH * 4 + mf][NH * 2 + nf] = __builtin_amdgcn_mfma_f32_16x16x32_bf16(
            af[mf * 2 + kk], bf_[nf * 2 + kk], acc[MH * 4 + mf][NH * 2 + nf], 0, 0, 0);
}

#define STAGE_A(slot, mh, kt) do {                                            \
  _Pragma("unroll") for (int j_ = 0; j_ < 2; ++j_)                            \
    __builtin_amdgcn_global_load_lds(                                         \
        GLB_SRC(pA + (long)(j_ * 128 + (mh) * 64) * K + (kt)),                \
        LDS_DST(smem + (slot) * 65536 + (arow0 + j_ * 128 + (mh) * 64) * 128),\
        16, 0, 0);                                                            \
} while (0)

#define STAGE_B(slot, nh, kt) do {                                            \
  _Pragma("unroll") for (int j_ = 0; j_ < 2; ++j_)                            \
    __builtin_amdgcn_global_load_lds(                                         \
        GLB_SRC(pB + (long)(j_ * 128 + (nh) * 32) * K + (kt)),                \
        LDS_DST(smem + (slot) * 65536 + 32768 +                               \
                (brow0 + j_ * 128 + (nh) * 32) * 128),                        \
        16, 0, 0);                                                            \
} while (0)

// write acc round RD (compile-time) into chunk buffer eb (64 rows x 256 cols)
#define EWRITE(RD, eb) do {                                                   \
  _Pragma("unroll") for (int fi = 0; fi < 2; ++fi)                            \
  _Pragma("unroll") for (int nf = 0; nf < 4; ++nf)                            \
  _Pragma("unroll") for (int r = 0; r < 4; ++r) {                             \
    const int lr2 = wr * 32 + fi * 16 + lg * 4 + r;                           \
    (eb)[lr2 * 256 + wc * 64 + nf * 16 + l15] = acc[(RD) * 2 + fi][nf][r];    \
  }                                                                           \
} while (0)

// MODE 0: bf16 out = acc + bias[n] (z=1 uses alt pointer set A2/B2/bias2/C2)
// MODE 1: bf16 out = mask ? sigmoid(acc) : 0 (mask read int32, direct)
// MODE 2: f32 out = acc
template <int MODE>
__global__ void __launch_bounds__(512, 2)
gemm8p_kernel(const bf16_t* __restrict__ A, const bf16_t* __restrict__ B,
              const float* __restrict__ bias, const int* __restrict__ mask,
              void* __restrict__ Cout, int M, int N, int K,
              long sA, long sB, long sC, long sMask,
              const bf16_t* __restrict__ A2, const bf16_t* __restrict__ B2,
              const float* __restrict__ bias2, void* __restrict__ C2) {
  __shared__ __align__(1024) char smem[131072];

  // ---- bijective XCD chunking (m204) + supertile decode (R9) ----
  const int gx = gridDim.x, gy = gridDim.y;
  int f0 = blockIdx.x + gx * (blockIdx.y + gy * blockIdx.z);
  const int nwg = gx * gy * (int)gridDim.z;
  const int q8 = nwg >> 3, r8 = nwg & 7;
  const int xcd = f0 & 7, idx = f0 >> 3;
  int f1 = (xcd < r8 ? xcd * (q8 + 1) : r8 * (q8 + 1) + (xcd - r8) * q8) + idx;
  int bxi, byi, bz;
  if constexpr (MODE == 1) {
    // supertile = 8bx x 2by; f1 = bx + 8*(by&1) + 16*((by>>1) + 4*bz)
    bxi = f1 & 7;
    const int byL = (f1 >> 3) & 1;
    const int st = (f1 >> 4) & 3;
    bz = f1 >> 6;
    byi = st * 2 + byL;
  } else {
    // by-major: f1 = by + gy*(bx + gx*bz)
    byi = f1 % gy;
    const int t = f1 / gy;
    bxi = t % gx;
    bz = t / gx;
  }

  const bf16_t* Ab; const bf16_t* Bb;
  const float* biasp = bias; void* Cp = Cout;
  if constexpr (MODE == 0) {
    if (bz) { Ab = A2; Bb = B2; biasp = bias2; Cp = C2; }
    else    { Ab = A;  Bb = B; }
  } else {
    Ab = A + bz * sA; Bb = B + bz * sB;
  }
  const int bm = bxi * 256, bn = byi * 256;
  const int tid = threadIdx.x;
  const int wave = tid >> 6, lane = tid & 63;
  const int wr = wave >> 2, wc = wave & 3;
  const int l15 = lane & 15, lg = lane >> 4;
  const int xk0 = (lg * 16) ^ ((lane & 7) << 4);
  const int NT = K >> 6;

  // staging bases
  const int lr = lane >> 3;
  const int cgs = ((lane & 7) ^ lr) * 8;
  const int arow0 = wave * 8;
  const int brow0 = (wave >> 2) * 64 + (wave & 3) * 8;
  const bf16_t* pA = Ab + (long)(bm + arow0 + lr) * K + cgs;
  const bf16_t* pB = Bb + (long)(bn + brow0 + lr) * K + cgs;

  // ds_read base offsets
  const int aoff = wr * 16384 + l15 * 128;          // + slot*65536 + mh*8192
  const int boff = 32768 + wc * 8192 + l15 * 128;   // + slot*65536 + nh*4096

  f32x4 acc[8][4] = {};
  bf16x8 afX[8], bfB[4], bf0[4];

  // ---- prologue: t0 full (8 instrs), then A0/B0(1) (4), B1/A1(1) (4) ----
  STAGE_A(0, 0, 0); STAGE_B(0, 0, 0); STAGE_B(0, 1, 0); STAGE_A(0, 1, 0);
  STAGE_A(1, 0, 64); STAGE_B(1, 0, 64);
  STAGE_B(1, 1, 64); STAGE_A(1, 1, 64);
  WVM8();   // tile0's 8 instrs landed
  SBAR();
  read_A(smem, aoff + 0, afX, xk0);   // A0(t0)
  read_B(smem, boff + 0, bf0, xk0);   // B0(t0)

  int slot = 0;
  for (int t = 0; t + 2 < NT; ++t) {
    const int so = slot * 65536, sn = (slot ^ 1) * 65536;
    const int k2 = (t + 2) << 6;
    // ---- P_a ----
    read_B(smem, so + boff + 4096, bfB, xk0);        // B1(t)
    STAGE_A(slot, 0, k2); STAGE_B(slot, 0, k2);      // A0(t+2), B0(t+2)
    SP1(); mfma_q<0, 0>(afX, bf0, acc); SP0();
    SP1(); mfma_q<0, 1>(afX, bfB, acc); SP0();
    read_A(smem, so + aoff + 8192, afX, xk0);        // A1(t)
    WVM8(); SBAR();                                  // c1
    // ---- P_b ----
    SP1(); mfma_q<1, 1>(afX, bfB, acc); SP0();
    SP1(); mfma_q<1, 0>(afX, bf0, acc); SP0();
    read_A(smem, sn + aoff + 0, afX, xk0);           // A0(t+1)
    read_B(smem, sn + boff + 0, bf0, xk0);           // B0(t+1)
    STAGE_B(slot, 1, k2); STAGE_A(slot, 1, k2);      // B1(t+2), A1(t+2)
    WVM8(); SBAR();                                  // c2
    slot ^= 1;
  }

  // ---- drain: tiles NT-2 (so), NT-1 (sn); no staging ----
  {
    const int so = slot * 65536, sn = (slot ^ 1) * 65536;
    read_B(smem, so + boff + 4096, bfB, xk0);        // B1(NT-2)
    SP1(); mfma_q<0, 0>(afX, bf0, acc); SP0();
    SP1(); mfma_q<0, 1>(afX, bfB, acc); SP0();
    read_A(smem, so + aoff + 8192, afX, xk0);        // A1(NT-2)
    WVM4(); SBAR();
    SP1(); mfma_q<1, 1>(afX, bfB, acc); SP0();
    SP1(); mfma_q<1, 0>(afX, bf0, acc); SP0();
    read_A(smem, sn + aoff + 0, afX, xk0);           // A0(NT-1)
    read_B(smem, sn + boff + 0, bf0, xk0);           // B0(NT-1)
    WVM0(); SBAR();
    // last tile
    read_B(smem, sn + boff + 4096, bfB, xk0);        // B1(NT-1)
    SP1(); mfma_q<0, 0>(afX, bf0, acc); SP0();
    SP1(); mfma_q<0, 1>(afX, bfB, acc); SP0();
    read_A(smem, sn + aoff + 8192, afX, xk0);        // A1(NT-1)
    SP1(); mfma_q<1, 1>(afX, bfB, acc); SP0();
    SP1(); mfma_q<1, 0>(afX, bf0, acc); SP0();
  }

  // ---- C-write: 4 rounds, double-buffered 64KB chunks, 1 barrier/round ----
  // (fully unrolled: acc/mask indices compile-time -- rule #20)
  float* eb0 = (float*)smem;
  float* eb1 = (float*)(smem + 65536);
  const int lrow = tid >> 3, t7 = tid & 7;
  const int growt0 = lrow + ((lrow >> 5) * 96);      // row map (wr0|wr1 halves)
  int4 m4a[8], m4b[8];
  if constexpr (MODE == 1) {
    const int* mrow = mask + bz * sMask + (long)(bm + growt0) * N + bn;
#pragma unroll
    for (int q = 0; q < 8; ++q)
      m4a[q] = *reinterpret_cast<const int4*>(mrow + (q * 8 + t7) * 4);
  }
  EWRITE(0, eb0);
  __syncthreads();
#pragma unroll
  for (int rd = 0; rd < 4; ++rd) {
    // prefetch next round's mask (uses the buffer NOT consumed this round)
    if constexpr (MODE == 1) {
      if (rd < 3) {
        const int* mrow =
            mask + bz * sMask + (long)(bm + (rd + 1) * 32 + growt0) * N + bn;
        if ((rd & 1) == 0) {
#pragma unroll
          for (int q = 0; q < 8; ++q)
            m4b[q] = *reinterpret_cast<const int4*>(mrow + (q * 8 + t7) * 4);
        } else {
#pragma unroll
          for (int q = 0; q < 8; ++q)
            m4a[q] = *reinterpret_cast<const int4*>(mrow + (q * 8 + t7) * 4);
        }
      }
    }
    // stage next round's acc into the other buffer (overlaps with emission)
    if (rd < 3) {
      if ((rd & 1) == 0) { EWRITE(rd + 1, eb1); } else { EWRITE(rd + 1, eb0); }
    }
    // emit this round from its buffer
    const float* eb = ((rd & 1) == 0) ? eb0 : eb1;
    const long rowbase = (long)(bm + rd * 32 + growt0) * N + bn;
#pragma unroll
    for (int q = 0; q < 8; ++q) {
      const int c4 = (q * 8 + t7) * 4;
      const f32x4 v = *reinterpret_cast<const f32x4*>(&eb[lrow * 256 + c4]);
      if constexpr (MODE == 1) {
        const int4 mq = ((rd & 1) == 0) ? m4a[q] : m4b[q];
        bf16x4 o;
        o[0] = (bf16_t)(mq.x ? __builtin_amdgcn_rcpf(1.f + __expf(-v[0])) : 0.f);
        o[1] = (bf16_t)(mq.y ? __builtin_amdgcn_rcpf(1.f + __expf(-v[1])) : 0.f);
        o[2] = (bf16_t)(mq.z ? __builtin_amdgcn_rcpf(1.f + __expf(-v[2])) : 0.f);
        o[3] = (bf16_t)(mq.w ? __builtin_amdgcn_rcpf(1.f + __expf(-v[3])) : 0.f);
        *reinterpret_cast<bf16x4*>((bf16_t*)Cp + bz * sC + rowbase + c4) = o;
      } else if constexpr (MODE == 0) {
        const f32x4 b4 = *reinterpret_cast<const f32x4*>(biasp + bn + c4);
        bf16x4 o;
        o[0] = (bf16_t)(v[0] + b4[0]); o[1] = (bf16_t)(v[1] + b4[1]);
        o[2] = (bf16_t)(v[2] + b4[2]); o[3] = (bf16_t)(v[3] + b4[3]);
        *reinterpret_cast<bf16x4*>((bf16_t*)Cp + bz * sC + rowbase + c4) = o;
      } else {
        *reinterpret_cast<f32x4*>((float*)Cp + bz * sC + rowbase + c4) = v;
      }
    }
    __syncthreads();   // protects: reads of this buffer done before rd+2 write
  }
}

extern "C" void kernel_launch(void* const* d_in, const int* in_sizes, int n_in,
                              void* d_out, int out_size, void* d_ws, size_t ws_size,
                              hipStream_t stream) {
  const float* queries = (const float*)d_in[0];
  const float* values  = (const float*)d_in[1];
  const int*   mask    = (const int*)d_in[2];
  const float* Wq = (const float*)d_in[3];
  const float* bq = (const float*)d_in[4];
  const float* Wk = (const float*)d_in[5];
  const float* bk = (const float*)d_in[6];
  const float* Wv = (const float*)d_in[7];
  const float* bv = (const float*)d_in[8];

  // B=8, L=2048, D=768. Workspace layout (bytes):
  char* ws = (char*)d_ws;
  bf16_t* qb  = (bf16_t*)(ws + 0);          // queries bf16   25165824
  bf16_t* vb  = (bf16_t*)(ws + 25165824);   // values bf16    25165824
  bf16_t* wqb = (bf16_t*)(ws + 50331648);   // Wq bf16         1179648
  bf16_t* wkb = (bf16_t*)(ws + 51511296);   // Wk bf16         1179648
  bf16_t* wvb = (bf16_t*)(ws + 52690944);   // Wv bf16         1179648
  bf16_t* qp  = (bf16_t*)(ws + 53870592);   // q_proj         25165824
  bf16_t* vp  = (bf16_t*)(ws + 79036416);   // v_proj         25165824
  bf16_t* kp  = (bf16_t*)(ws + 104202240);  // k_proj         25165824
  bf16_t* vpT = (bf16_t*)(ws + 129368064);  // v_proj^T       25165824
  bf16_t* P   = (bf16_t*)(ws + 154533888);  // sigmoid scores 67108864
  // total: 221642752

  // converts (q, v, 3 weights) in one launch, 4 float4/thread
  convert_kernel<<<6576, 256, 0, stream>>>(queries, values, Wq, Wk, Wv,
                                           qb, vb, wqb, wkb, wvb);

  const dim3 blk2(512);

  // q-proj & v-proj batched (independent): z=0 qb*Wq+bq->qp, z=1 vb*Wv+bv->vp
  gemm8p_kernel<0><<<dim3(64, 3, 2), blk2, 0, stream>>>(
      qb, wqb, bq, nullptr, qp, 16384, 768, 768, 0, 0, 0, 0,
      vb, wvb, bv, vp);
  // k-proj (faithful quirk: k = Linear_k(v_proj))
  gemm8p_kernel<0><<<dim3(64, 3, 1), blk2, 0, stream>>>(
      vp, wkb, bk, nullptr, kp, 16384, 768, 768, 0, 0, 0, 0,
      vp, wkb, bk, kp);

  // v_proj [b][2048][768] -> v_projT [b][768][2048]
  transpose_bf16_kernel<<<dim3(32, 12, 8), 256, 0, stream>>>(vp, vpT, 2048, 768);

  // P = sigmoid(mask(q k^T)) : per batch [2048,2048], K=768; int32 mask direct
  gemm8p_kernel<1><<<dim3(8, 8, 8), blk2, 0, stream>>>(
      qp, kp, nullptr, mask, P, 2048, 2048, 768,
      (long)2048 * 768, (long)2048 * 768, (long)2048 * 2048, (long)2048 * 2048,
      nullptr, nullptr, nullptr, nullptr);

  // context = P v : per batch [2048,768], K=2048, fp32 out
  gemm8p_kernel<2><<<dim3(8, 3, 8), blk2, 0, stream>>>(
      P, vpT, nullptr, nullptr, d_out, 2048, 768, 2048,
      (long)2048 * 2048, (long)768 * 2048, (long)2048 * 768, 0,
      nullptr, nullptr, nullptr, nullptr);
}